// Round 3
// baseline (976.490 us; speedup 1.0000x reference)
//
#include <hip/hip_runtime.h>
#include <hip/hip_bf16.h>

// Problem constants
constexpr int BB = 2, PP = 64, NN = 256, CC = 512, HH = 8, HD = 64, MLPD = 2048;
constexpr int BP = BB * PP;       // 128
constexpr int MTOT = BP * NN;     // 32768
constexpr float EPS = 1e-5f;

typedef __attribute__((ext_vector_type(8))) short short8_t;
typedef __attribute__((ext_vector_type(4))) float f32x4_t;

__device__ inline unsigned short f2bf(float f) {
  union { float f; unsigned u; } v; v.f = f;
  unsigned r = v.u + 0x7fffu + ((v.u >> 16) & 1u);
  return (unsigned short)(r >> 16);
}

// ---------------- f32 -> bf16 convert (weights) ----------------
__global__ void k_f2bf(const float* __restrict__ in, unsigned short* __restrict__ out, int n) {
  int i = blockIdx.x * blockDim.x + threadIdx.x;
  int stride = gridDim.x * blockDim.x;
  for (; i < n; i += stride) out[i] = f2bf(in[i]);
}

// ---------------- group norm over N (tokens), per (bp, c) ----------------
// grid: BP*2 blocks, 256 threads; each thread owns one (bp, c) column.
__global__ void k_gn(const float* __restrict__ x, const float* __restrict__ w,
                     const float* __restrict__ b, unsigned short* __restrict__ out) {
  int bp = blockIdx.x >> 1;
  int c = ((blockIdx.x & 1) << 8) + threadIdx.x;
  const float* xp = x + (size_t)bp * NN * CC + c;
  float s = 0.f, sq = 0.f;
  for (int n = 0; n < NN; ++n) { float v = xp[(size_t)n * CC]; s += v; sq += v * v; }
  float mean = s * (1.f / NN);
  float var = sq * (1.f / NN) - mean * mean;
  float rstd = rsqrtf(var + EPS);
  float ww = w[c], bb = b[c];
  unsigned short* op = out + (size_t)bp * NN * CC + c;
  for (int n = 0; n < NN; ++n) {
    float v = xp[(size_t)n * CC];
    op[(size_t)n * CC] = f2bf((v - mean) * rstd * ww + bb);
  }
}

// ---------------- bf16 MFMA GEMM, C = A @ B^T + bias (B is [Nn][K] row-major) ----------------
// EPI 0: out bf16 = v + bias
// EPI 1: out bf16 = gelu(v + bias)
// EPI 2: out f32  = resid + v + bias
template <int EPI>
__global__ __launch_bounds__(256) void k_gemm(const unsigned short* __restrict__ A,
                                              const unsigned short* __restrict__ Bw,
                                              const float* __restrict__ bias,
                                              const float* __restrict__ resid,
                                              unsigned short* __restrict__ outb,
                                              float* __restrict__ outf,
                                              int M, int Nn, int K) {
  constexpr int BM = 128, BN = 128, BK = 64, LDT = BK + 16; // 80 elems, 160B row (16B aligned)
  __shared__ unsigned short As[BM * LDT];
  __shared__ unsigned short Bs[BN * LDT];
  int tid = threadIdx.x;
  int lane = tid & 63, w = tid >> 6;
  int wm = w >> 1, wn = w & 1;
  int m0 = blockIdx.y * BM, n0 = blockIdx.x * BN;
  f32x4_t acc[4][4] = {};
  for (int k0 = 0; k0 < K; k0 += BK) {
#pragma unroll
    for (int p = 0; p < 4; ++p) {
      int idx = p * 256 + tid;
      int r = idx >> 3, ch = idx & 7;
      *(short8_t*)&As[r * LDT + ch * 8] = *(const short8_t*)&A[(size_t)(m0 + r) * K + k0 + ch * 8];
    }
#pragma unroll
    for (int p = 0; p < 4; ++p) {
      int idx = p * 256 + tid;
      int r = idx >> 3, ch = idx & 7;
      *(short8_t*)&Bs[r * LDT + ch * 8] = *(const short8_t*)&Bw[(size_t)(n0 + r) * K + k0 + ch * 8];
    }
    __syncthreads();
    int lr = lane & 15, lk8 = (lane >> 4) * 8;
#pragma unroll
    for (int kk = 0; kk < BK; kk += 32) {
      short8_t af[4], bfr[4];
#pragma unroll
      for (int i = 0; i < 4; ++i) af[i] = *(const short8_t*)&As[(wm * 64 + i * 16 + lr) * LDT + kk + lk8];
#pragma unroll
      for (int j = 0; j < 4; ++j) bfr[j] = *(const short8_t*)&Bs[(wn * 64 + j * 16 + lr) * LDT + kk + lk8];
#pragma unroll
      for (int i = 0; i < 4; ++i)
#pragma unroll
        for (int j = 0; j < 4; ++j)
          acc[i][j] = __builtin_amdgcn_mfma_f32_16x16x32_bf16(af[i], bfr[j], acc[i][j], 0, 0, 0);
    }
    __syncthreads();
  }
  int lr = lane & 15, lg = lane >> 4;
#pragma unroll
  for (int i = 0; i < 4; ++i)
#pragma unroll
    for (int j = 0; j < 4; ++j) {
      int col = n0 + wn * 64 + j * 16 + lr;
      float bv = bias[col];
#pragma unroll
      for (int r2 = 0; r2 < 4; ++r2) {
        int row = m0 + wm * 64 + i * 16 + lg * 4 + r2;
        float v = acc[i][j][r2] + bv;
        size_t off = (size_t)row * Nn + col;
        if (EPI == 0) {
          outb[off] = f2bf(v);
        } else if (EPI == 1) {
          float g = 0.5f * v * (1.f + erff(v * 0.70710678118f));
          outb[off] = f2bf(g);
        } else {
          outf[off] = resid[off] + v;
        }
      }
    }
}

// ---------------- fused attention ----------------
// grid: (4 q-tiles, H, BP); 256 threads = 4 waves; each wave owns 16 q rows.
__global__ __launch_bounds__(256) void k_attn(const unsigned short* __restrict__ qkv,
                                              const int* __restrict__ mask,
                                              const float* __restrict__ pos,
                                              unsigned short* __restrict__ attn_out) {
  constexpr int LKD = HD + 16;  // 80 elem stride (160B, 16B aligned)
  constexpr int LMD = NN + 8;   // 264 elem stride (528B, 16B aligned)
  __shared__ unsigned short qs[64 * LKD];    // 10 KB
  __shared__ unsigned short ks[NN * LKD];    // 40 KB
  __shared__ unsigned short vts[HD * LMD];   // 33.75 KB  (vT[d][m])
  __shared__ unsigned short ps[64 * LMD];    // 33.75 KB  (P[qrow][m])
  int qt = blockIdx.x, h = blockIdx.y, bp = blockIdx.z;
  int tid = threadIdx.x, lane = tid & 63, w = tid >> 6;
  int q0 = qt * 64;
  const size_t QROW = 3 * CC;  // 1536
  const unsigned short* qbase = qkv + (size_t)(bp * NN) * QROW + h * HD;
  const unsigned short* kbase = qbase + CC;
  const unsigned short* vbase = qbase + 2 * CC;
  // stage Q (64x64)
#pragma unroll
  for (int p1 = 0; p1 < 2; ++p1) {
    int idx = p1 * 256 + tid;
    int r = idx >> 3, ch = idx & 7;
    *(short8_t*)&qs[r * LKD + ch * 8] = *(const short8_t*)&qbase[(size_t)(q0 + r) * QROW + ch * 8];
  }
  // stage K (256x64)
#pragma unroll
  for (int p1 = 0; p1 < 8; ++p1) {
    int idx = p1 * 256 + tid;
    int r = idx >> 3, ch = idx & 7;
    *(short8_t*)&ks[r * LKD + ch * 8] = *(const short8_t*)&kbase[(size_t)r * QROW + ch * 8];
  }
  // stage V transposed: vts[d][m] (m contiguous)
#pragma unroll
  for (int p1 = 0; p1 < 8; ++p1) {
    int idx = p1 * 256 + tid;
    int m = idx >> 3, dch = idx & 7;
    short8_t vv = *(const short8_t*)&vbase[(size_t)m * QROW + dch * 8];
#pragma unroll
    for (int j = 0; j < 8; ++j) vts[(dch * 8 + j) * LMD + m] = (unsigned short)vv[j];
  }
  __syncthreads();
  // QK^T : per-wave 16 q rows x 256 k cols
  f32x4_t sc[16] = {};
  int lr = lane & 15, lg = lane >> 4;
#pragma unroll
  for (int kk = 0; kk < HD; kk += 32) {
    short8_t a = *(const short8_t*)&qs[(w * 16 + lr) * LKD + kk + lg * 8];
#pragma unroll
    for (int f = 0; f < 16; ++f) {
      short8_t b = *(const short8_t*)&ks[(f * 16 + lr) * LKD + kk + lg * 8];
      sc[f] = __builtin_amdgcn_mfma_f32_16x16x32_bf16(a, b, sc[f], 0, 0, 0);
    }
  }
  // mask + pos + softmax (rows fully resident: cols 0..255)
  const float scale = 0.125f;  // 1/sqrt(64)
#pragma unroll
  for (int r2 = 0; r2 < 4; ++r2) {
    int qrow = q0 + w * 16 + lg * 4 + r2;
    const float* posp = pos + ((size_t)h * NN + qrow) * NN;
    const int* mp = mask + ((size_t)bp * NN + qrow) * NN;
    float sv[16];
    float mx = -3.0e38f;
#pragma unroll
    for (int f = 0; f < 16; ++f) {
      int col = f * 16 + lr;
      float s = (mp[col] > 0) ? (sc[f][r2] * scale + posp[col]) : -1.0e9f;
      sv[f] = s;
      mx = fmaxf(mx, s);
    }
    for (int d2 = 1; d2 < 16; d2 <<= 1) mx = fmaxf(mx, __shfl_xor(mx, d2));
    float sum = 0.f;
#pragma unroll
    for (int f = 0; f < 16; ++f) { float e = expf(sv[f] - mx); sv[f] = e; sum += e; }
    for (int d2 = 1; d2 < 16; d2 <<= 1) sum += __shfl_xor(sum, d2);
    float inv = 1.f / sum;
    int prow = w * 16 + lg * 4 + r2;
#pragma unroll
    for (int f = 0; f < 16; ++f) ps[prow * LMD + f * 16 + lr] = f2bf(sv[f] * inv);
  }
  __syncthreads();
  // PV: per-wave 16 rows x 64 cols, K=256
  f32x4_t ao[4] = {};
#pragma unroll
  for (int kk = 0; kk < NN; kk += 32) {
    short8_t a = *(const short8_t*)&ps[(w * 16 + lr) * LMD + kk + lg * 8];
#pragma unroll
    for (int f = 0; f < 4; ++f) {
      short8_t b = *(const short8_t*)&vts[(f * 16 + lr) * LMD + kk + lg * 8];
      ao[f] = __builtin_amdgcn_mfma_f32_16x16x32_bf16(a, b, ao[f], 0, 0, 0);
    }
  }
#pragma unroll
  for (int f = 0; f < 4; ++f)
#pragma unroll
    for (int r2 = 0; r2 < 4; ++r2) {
      int token = bp * NN + q0 + w * 16 + lg * 4 + r2;
      int d = f * 16 + lr;
      attn_out[(size_t)token * CC + h * HD + d] = f2bf(ao[f][r2]);
    }
}

extern "C" void kernel_launch(void* const* d_in, const int* in_sizes, int n_in,
                              void* d_out, int out_size, void* d_ws, size_t ws_size,
                              hipStream_t stream) {
  const float* x      = (const float*)d_in[0];
  const int*   mask   = (const int*)d_in[1];
  const float* pos    = (const float*)d_in[2];
  const float* n1w    = (const float*)d_in[3];
  const float* n1b    = (const float*)d_in[4];
  const float* qkv_w  = (const float*)d_in[5];
  const float* qkv_b  = (const float*)d_in[6];
  const float* proj_w = (const float*)d_in[7];
  const float* proj_b = (const float*)d_in[8];
  const float* n2w    = (const float*)d_in[9];
  const float* n2b    = (const float*)d_in[10];
  const float* w1     = (const float*)d_in[11];
  const float* b1     = (const float*)d_in[12];
  const float* w2     = (const float*)d_in[13];
  const float* b2     = (const float*)d_in[14];
  float* out = (float*)d_out;
  char* ws = (char*)d_ws;

  size_t off = 0;
  auto alloc = [&](size_t bytes) { size_t o = off; off += (bytes + 255) & ~(size_t)255; return o; };
  unsigned short* wqkv  = (unsigned short*)(ws + alloc((size_t)3 * CC * CC * 2));
  unsigned short* wproj = (unsigned short*)(ws + alloc((size_t)CC * CC * 2));
  unsigned short* wm1   = (unsigned short*)(ws + alloc((size_t)MLPD * CC * 2));
  unsigned short* wm2   = (unsigned short*)(ws + alloc((size_t)CC * MLPD * 2));
  unsigned short* xn    = (unsigned short*)(ws + alloc((size_t)MTOT * CC * 2));   // 32 MB (also reused as xn2)
  float*          x1    = (float*)(ws + alloc((size_t)MTOT * CC * 4));            // 64 MB
  size_t region = alloc((size_t)MTOT * MLPD * 2);                                 // 128 MB shared region
  unsigned short* qkvb  = (unsigned short*)(ws + region);                          // 96 MB
  unsigned short* attnb = (unsigned short*)(ws + region + (size_t)MTOT * 3 * CC * 2); // 32 MB
  unsigned short* hbuf  = (unsigned short*)(ws + region);                          // 128 MB (overlaps dead qkv+attn)

  // weight conversions
  k_f2bf<<<1024, 256, 0, stream>>>(qkv_w, wqkv, 3 * CC * CC);
  k_f2bf<<<1024, 256, 0, stream>>>(proj_w, wproj, CC * CC);
  k_f2bf<<<1024, 256, 0, stream>>>(w1, wm1, MLPD * CC);
  k_f2bf<<<1024, 256, 0, stream>>>(w2, wm2, CC * MLPD);

  // norm1
  k_gn<<<BP * 2, 256, 0, stream>>>(x, n1w, n1b, xn);
  // qkv = xn @ qkv_w^T + b
  k_gemm<0><<<dim3(3 * CC / 128, MTOT / 128), 256, 0, stream>>>(xn, wqkv, qkv_b, nullptr, qkvb, nullptr, MTOT, 3 * CC, CC);
  // attention
  k_attn<<<dim3(4, HH, BP), 256, 0, stream>>>(qkvb, mask, pos, attnb);
  // x1 = x + attn @ proj_w^T + proj_b
  k_gemm<2><<<dim3(CC / 128, MTOT / 128), 256, 0, stream>>>(attnb, wproj, proj_b, x, nullptr, x1, MTOT, CC, CC);
  // norm2
  k_gn<<<BP * 2, 256, 0, stream>>>(x1, n2w, n2b, xn);
  // h = gelu(xn @ w1^T + b1)
  k_gemm<1><<<dim3(MLPD / 128, MTOT / 128), 256, 0, stream>>>(xn, wm1, b1, nullptr, hbuf, nullptr, MTOT, MLPD, CC);
  // out = x1 + h @ w2^T + b2
  k_gemm<2><<<dim3(CC / 128, MTOT / 128), 256, 0, stream>>>(hbuf, wm2, b2, x1, nullptr, out, MTOT, CC, MLPD);
}

// Round 4
// 707.553 us; speedup vs baseline: 1.3801x; 1.3801x over previous
//
#include <hip/hip_runtime.h>
#include <hip/hip_bf16.h>

// Problem constants
constexpr int BB = 2, PP = 64, NN = 256, CC = 512, HH = 8, HD = 64, MLPD = 2048;
constexpr int BP = BB * PP;       // 128
constexpr int MTOT = BP * NN;     // 32768
constexpr float EPS = 1e-5f;

typedef __attribute__((ext_vector_type(8))) short short8_t;
typedef __attribute__((ext_vector_type(4))) short short4_t;
typedef __attribute__((ext_vector_type(4))) float f32x4_t;

__device__ inline unsigned short f2bf(float f) {
  union { float f; unsigned u; } v; v.f = f;
  unsigned r = v.u + 0x7fffu + ((v.u >> 16) & 1u);
  return (unsigned short)(r >> 16);
}

// ---------------- f32 -> bf16 convert (weights) ----------------
__global__ void k_f2bf(const float* __restrict__ in, unsigned short* __restrict__ out, int n) {
  int i = blockIdx.x * blockDim.x + threadIdx.x;
  int stride = gridDim.x * blockDim.x;
  for (; i < n; i += stride) out[i] = f2bf(in[i]);
}

// ---------------- group norm over N (tokens), per (bp, c) ----------------
__global__ void k_gn(const float* __restrict__ x, const float* __restrict__ w,
                     const float* __restrict__ b, unsigned short* __restrict__ out) {
  int bp = blockIdx.x >> 1;
  int c = ((blockIdx.x & 1) << 8) + threadIdx.x;
  const float* xp = x + (size_t)bp * NN * CC + c;
  float s = 0.f, sq = 0.f;
  for (int n = 0; n < NN; ++n) { float v = xp[(size_t)n * CC]; s += v; sq += v * v; }
  float mean = s * (1.f / NN);
  float var = sq * (1.f / NN) - mean * mean;
  float rstd = rsqrtf(var + EPS);
  float ww = w[c], bb = b[c];
  unsigned short* op = out + (size_t)bp * NN * CC + c;
  for (int n = 0; n < NN; ++n) {
    float v = xp[(size_t)n * CC];
    op[(size_t)n * CC] = f2bf((v - mean) * rstd * ww + bb);
  }
}

// ---------------- bf16 MFMA GEMM, C = A @ B^T + bias (B is [Nn][K] row-major) ----------------
// EPI 0: out bf16 = v + bias
// EPI 1: out bf16 = gelu(v + bias)
// EPI 2: out f32  = resid + v + bias
// EPI 3: qkv split-store: Q -> qb[bp*H+h][m][d], K -> kb[...], V -> vtb[bp*H+h][d][m] (transposed)
template <int EPI>
__global__ __launch_bounds__(256) void k_gemm(const unsigned short* __restrict__ A,
                                              const unsigned short* __restrict__ Bw,
                                              const float* __restrict__ bias,
                                              const float* __restrict__ resid,
                                              unsigned short* __restrict__ outb,
                                              float* __restrict__ outf,
                                              unsigned short* __restrict__ qb,
                                              unsigned short* __restrict__ kb,
                                              unsigned short* __restrict__ vtb,
                                              int M, int Nn, int K) {
  constexpr int BM = 128, BN = 128, BK = 64, LDT = BK + 16; // 80 elems, 160B row
  __shared__ unsigned short As[BM * LDT];
  __shared__ unsigned short Bs[BN * LDT];
  int tid = threadIdx.x;
  int lane = tid & 63, w = tid >> 6;
  int wm = w >> 1, wn = w & 1;
  int m0 = blockIdx.y * BM, n0 = blockIdx.x * BN;
  f32x4_t acc[4][4] = {};
  for (int k0 = 0; k0 < K; k0 += BK) {
#pragma unroll
    for (int p = 0; p < 4; ++p) {
      int idx = p * 256 + tid;
      int r = idx >> 3, ch = idx & 7;
      *(short8_t*)&As[r * LDT + ch * 8] = *(const short8_t*)&A[(size_t)(m0 + r) * K + k0 + ch * 8];
    }
#pragma unroll
    for (int p = 0; p < 4; ++p) {
      int idx = p * 256 + tid;
      int r = idx >> 3, ch = idx & 7;
      *(short8_t*)&Bs[r * LDT + ch * 8] = *(const short8_t*)&Bw[(size_t)(n0 + r) * K + k0 + ch * 8];
    }
    __syncthreads();
    int lr = lane & 15, lk8 = (lane >> 4) * 8;
#pragma unroll
    for (int kk = 0; kk < BK; kk += 32) {
      short8_t af[4], bfr[4];
#pragma unroll
      for (int i = 0; i < 4; ++i) af[i] = *(const short8_t*)&As[(wm * 64 + i * 16 + lr) * LDT + kk + lk8];
#pragma unroll
      for (int j = 0; j < 4; ++j) bfr[j] = *(const short8_t*)&Bs[(wn * 64 + j * 16 + lr) * LDT + kk + lk8];
#pragma unroll
      for (int i = 0; i < 4; ++i)
#pragma unroll
        for (int j = 0; j < 4; ++j)
          acc[i][j] = __builtin_amdgcn_mfma_f32_16x16x32_bf16(af[i], bfr[j], acc[i][j], 0, 0, 0);
    }
    __syncthreads();
  }
  int lr = lane & 15, lg = lane >> 4;
#pragma unroll
  for (int i = 0; i < 4; ++i)
#pragma unroll
    for (int j = 0; j < 4; ++j) {
      int col = n0 + wn * 64 + j * 16 + lr;
      float bv = bias[col];
      int row0 = m0 + wm * 64 + i * 16 + lg * 4;
      if (EPI == 3) {
        int which = col >> 9;         // 0=q 1=k 2=v (wave-uniform)
        int hh2 = (col >> 6) & 7;     // head (wave-uniform)
        int d = col & 63;
        int bp_ = row0 >> 8, m = row0 & 255;   // 4 consecutive rows stay in one bp
        size_t hb = (size_t)(bp_ * HH + hh2);
        if (which == 2) {
          short4_t pk;
#pragma unroll
          for (int r2 = 0; r2 < 4; ++r2) pk[r2] = (short)f2bf(acc[i][j][r2] + bv);
          *(short4_t*)&vtb[(hb * HD + d) * NN + m] = pk;
        } else {
          unsigned short* dst = (which == 0) ? qb : kb;
#pragma unroll
          for (int r2 = 0; r2 < 4; ++r2)
            dst[(hb * NN + m + r2) * HD + d] = f2bf(acc[i][j][r2] + bv);
        }
      } else {
#pragma unroll
        for (int r2 = 0; r2 < 4; ++r2) {
          int row = row0 + r2;
          float v = acc[i][j][r2] + bv;
          size_t off = (size_t)row * Nn + col;
          if (EPI == 0) {
            outb[off] = f2bf(v);
          } else if (EPI == 1) {
            float g = 0.5f * v * (1.f + erff(v * 0.70710678118f));
            outb[off] = f2bf(g);
          } else {
            outf[off] = resid[off] + v;
          }
        }
      }
    }
}

// ---------------- fused attention v2: no K/V LDS staging, P-only LDS, 4 blocks/CU ----------------
// grid: (4 q-tiles, H, BP); 256 threads = 4 waves; each wave owns 16 q rows independently.
__global__ __launch_bounds__(256, 4) void k_attn2(const unsigned short* __restrict__ qb,
                                                  const unsigned short* __restrict__ kb,
                                                  const unsigned short* __restrict__ vtb,
                                                  const int* __restrict__ mask,
                                                  const float* __restrict__ pos,
                                                  unsigned short* __restrict__ attn_out) {
  constexpr int LMD = NN + 8;  // 264 elems; row stride 132 words -> 2-way conflict (free)
  __shared__ unsigned short ps[64 * LMD];  // 33.75 KB
  int qt = blockIdx.x, h = blockIdx.y, bp = blockIdx.z;
  int tid = threadIdx.x, lane = tid & 63, w = tid >> 6;
  int lr = lane & 15, lg = lane >> 4;
  int q0 = qt * 64;
  size_t bh = (size_t)(bp * HH + h);
  const unsigned short* Q = qb + bh * NN * HD;
  const unsigned short* K = kb + bh * NN * HD;
  const unsigned short* VT = vtb + bh * HD * NN;
  // Q fragments direct from global (16 rows per wave)
  short8_t qf0 = *(const short8_t*)&Q[(size_t)(q0 + w * 16 + lr) * HD + lg * 8];
  short8_t qf1 = *(const short8_t*)&Q[(size_t)(q0 + w * 16 + lr) * HD + 32 + lg * 8];
  // QK^T: 16 q rows x 256 k cols
  f32x4_t sc[16] = {};
#pragma unroll
  for (int f = 0; f < 16; ++f) {
    short8_t b0 = *(const short8_t*)&K[(size_t)(f * 16 + lr) * HD + lg * 8];
    sc[f] = __builtin_amdgcn_mfma_f32_16x16x32_bf16(qf0, b0, sc[f], 0, 0, 0);
    short8_t b1 = *(const short8_t*)&K[(size_t)(f * 16 + lr) * HD + 32 + lg * 8];
    sc[f] = __builtin_amdgcn_mfma_f32_16x16x32_bf16(qf1, b1, sc[f], 0, 0, 0);
  }
  // mask + pos + softmax, rows fully resident (in place in sc)
  const float scale = 0.125f;  // 1/sqrt(64)
#pragma unroll
  for (int r2 = 0; r2 < 4; ++r2) {
    int qrow = q0 + w * 16 + lg * 4 + r2;
    const float* posp = pos + ((size_t)h * NN + qrow) * NN;
    const int* mp = mask + ((size_t)bp * NN + qrow) * NN;
    float mx = -3.0e38f;
#pragma unroll
    for (int f = 0; f < 16; ++f) {
      int col = f * 16 + lr;
      float s = (mp[col] > 0) ? (sc[f][r2] * scale + posp[col]) : -1.0e9f;
      sc[f][r2] = s;
      mx = fmaxf(mx, s);
    }
    for (int d2 = 1; d2 < 16; d2 <<= 1) mx = fmaxf(mx, __shfl_xor(mx, d2));
    float sum = 0.f;
#pragma unroll
    for (int f = 0; f < 16; ++f) { float e = __expf(sc[f][r2] - mx); sc[f][r2] = e; sum += e; }
    for (int d2 = 1; d2 < 16; d2 <<= 1) sum += __shfl_xor(sum, d2);
    float inv = 1.f / sum;
    int prow = w * 16 + lg * 4 + r2;
#pragma unroll
    for (int f = 0; f < 16; ++f) ps[prow * LMD + f * 16 + lr] = f2bf(sc[f][r2] * inv);
  }
  // P rows are wave-private: no block barrier needed (compiler orders LDS within wave)
  f32x4_t ao[4] = {};
#pragma unroll
  for (int kt = 0; kt < 8; ++kt) {
    short8_t a = *(const short8_t*)&ps[(w * 16 + lr) * LMD + kt * 32 + lg * 8];
#pragma unroll
    for (int f = 0; f < 4; ++f) {
      short8_t b = *(const short8_t*)&VT[(size_t)(f * 16 + lr) * NN + kt * 32 + lg * 8];
      ao[f] = __builtin_amdgcn_mfma_f32_16x16x32_bf16(a, b, ao[f], 0, 0, 0);
    }
  }
#pragma unroll
  for (int f = 0; f < 4; ++f)
#pragma unroll
    for (int r2 = 0; r2 < 4; ++r2) {
      int token = bp * NN + q0 + w * 16 + lg * 4 + r2;
      int d = f * 16 + lr;
      attn_out[(size_t)token * CC + h * HD + d] = f2bf(ao[f][r2]);
    }
}

extern "C" void kernel_launch(void* const* d_in, const int* in_sizes, int n_in,
                              void* d_out, int out_size, void* d_ws, size_t ws_size,
                              hipStream_t stream) {
  const float* x      = (const float*)d_in[0];
  const int*   mask   = (const int*)d_in[1];
  const float* pos    = (const float*)d_in[2];
  const float* n1w    = (const float*)d_in[3];
  const float* n1b    = (const float*)d_in[4];
  const float* qkv_w  = (const float*)d_in[5];
  const float* qkv_b  = (const float*)d_in[6];
  const float* proj_w = (const float*)d_in[7];
  const float* proj_b = (const float*)d_in[8];
  const float* n2w    = (const float*)d_in[9];
  const float* n2b    = (const float*)d_in[10];
  const float* w1     = (const float*)d_in[11];
  const float* b1     = (const float*)d_in[12];
  const float* w2     = (const float*)d_in[13];
  const float* b2     = (const float*)d_in[14];
  float* out = (float*)d_out;
  char* ws = (char*)d_ws;

  size_t off = 0;
  auto alloc = [&](size_t bytes) { size_t o = off; off += (bytes + 255) & ~(size_t)255; return o; };
  unsigned short* wqkv  = (unsigned short*)(ws + alloc((size_t)3 * CC * CC * 2));
  unsigned short* wproj = (unsigned short*)(ws + alloc((size_t)CC * CC * 2));
  unsigned short* wm1   = (unsigned short*)(ws + alloc((size_t)MLPD * CC * 2));
  unsigned short* wm2   = (unsigned short*)(ws + alloc((size_t)CC * MLPD * 2));
  unsigned short* xn    = (unsigned short*)(ws + alloc((size_t)MTOT * CC * 2));   // 32 MB
  float*          x1    = (float*)(ws + alloc((size_t)MTOT * CC * 4));            // 64 MB
  size_t region = alloc((size_t)MTOT * MLPD * 2);                                 // 128 MB shared region
  const size_t BUFE = (size_t)MTOT * CC;  // elems per 32MB buffer
  unsigned short* qbuf  = (unsigned short*)(ws + region);
  unsigned short* kbuf  = qbuf + BUFE;
  unsigned short* vtbuf = qbuf + 2 * BUFE;
  unsigned short* attnb = qbuf + 3 * BUFE;
  unsigned short* hbuf  = (unsigned short*)(ws + region);  // reuses all 4 (dead by MLP time)

  // weight conversions
  k_f2bf<<<1024, 256, 0, stream>>>(qkv_w, wqkv, 3 * CC * CC);
  k_f2bf<<<1024, 256, 0, stream>>>(proj_w, wproj, CC * CC);
  k_f2bf<<<1024, 256, 0, stream>>>(w1, wm1, MLPD * CC);
  k_f2bf<<<1024, 256, 0, stream>>>(w2, wm2, CC * MLPD);

  // norm1
  k_gn<<<BP * 2, 256, 0, stream>>>(x, n1w, n1b, xn);
  // qkv = xn @ qkv_w^T + b, split-stored into q/k/v^T head-major buffers
  k_gemm<3><<<dim3(3 * CC / 128, MTOT / 128), 256, 0, stream>>>(xn, wqkv, qkv_b, nullptr, nullptr, nullptr, qbuf, kbuf, vtbuf, MTOT, 3 * CC, CC);
  // attention
  k_attn2<<<dim3(4, HH, BP), 256, 0, stream>>>(qbuf, kbuf, vtbuf, mask, pos, attnb);
  // x1 = x + attn @ proj_w^T + proj_b
  k_gemm<2><<<dim3(CC / 128, MTOT / 128), 256, 0, stream>>>(attnb, wproj, proj_b, x, nullptr, x1, nullptr, nullptr, nullptr, MTOT, CC, CC);
  // norm2
  k_gn<<<BP * 2, 256, 0, stream>>>(x1, n2w, n2b, xn);
  // h = gelu(xn @ w1^T + b1)
  k_gemm<1><<<dim3(MLPD / 128, MTOT / 128), 256, 0, stream>>>(xn, wm1, b1, nullptr, hbuf, nullptr, nullptr, nullptr, nullptr, MTOT, MLPD, CC);
  // out = x1 + h @ w2^T + b2
  k_gemm<2><<<dim3(CC / 128, MTOT / 128), 256, 0, stream>>>(hbuf, wm2, b2, x1, nullptr, out, nullptr, nullptr, nullptr, MTOT, CC, MLPD);
}

// Round 6
// 672.334 us; speedup vs baseline: 1.4524x; 1.0524x over previous
//
#include <hip/hip_runtime.h>
#include <hip/hip_bf16.h>

// Problem constants
constexpr int BB = 2, PP = 64, NN = 256, CC = 512, HH = 8, HD = 64, MLPD = 2048;
constexpr int BP = BB * PP;       // 128
constexpr int MTOT = BP * NN;     // 32768
constexpr float EPS = 1e-5f;

typedef __attribute__((ext_vector_type(8))) short short8_t;
typedef __attribute__((ext_vector_type(4))) short short4_t;
typedef __attribute__((ext_vector_type(4))) float f32x4_t;

__device__ inline unsigned short f2bf(float f) {
  union { float f; unsigned u; } v; v.f = f;
  unsigned r = v.u + 0x7fffu + ((v.u >> 16) & 1u);
  return (unsigned short)(r >> 16);
}

// async 16B global -> LDS (wave-uniform LDS base, per-lane global addr; HW writes base + lane*16)
__device__ inline void async_copy16(unsigned short* lds_base, const unsigned short* g) {
  __builtin_amdgcn_global_load_lds((const __attribute__((address_space(1))) unsigned int*)g,
                                   (__attribute__((address_space(3))) unsigned int*)lds_base,
                                   16, 0, 0);
}

// ---------------- f32 -> bf16 convert (weights) ----------------
__global__ void k_f2bf(const float* __restrict__ in, unsigned short* __restrict__ out, int n) {
  int i = blockIdx.x * blockDim.x + threadIdx.x;
  int stride = gridDim.x * blockDim.x;
  for (; i < n; i += stride) out[i] = f2bf(in[i]);
}

// ---------------- group norm over N (tokens), per (bp, c) ----------------
__global__ void k_gn(const float* __restrict__ x, const float* __restrict__ w,
                     const float* __restrict__ b, unsigned short* __restrict__ out) {
  int bp = blockIdx.x >> 1;
  int c = ((blockIdx.x & 1) << 8) + threadIdx.x;
  const float* xp = x + (size_t)bp * NN * CC + c;
  float s = 0.f, sq = 0.f;
  for (int n = 0; n < NN; ++n) { float v = xp[(size_t)n * CC]; s += v; sq += v * v; }
  float mean = s * (1.f / NN);
  float var = sq * (1.f / NN) - mean * mean;
  float rstd = rsqrtf(var + EPS);
  float ww = w[c], bb = b[c];
  unsigned short* op = out + (size_t)bp * NN * CC + c;
  for (int n = 0; n < NN; ++n) {
    float v = xp[(size_t)n * CC];
    op[(size_t)n * CC] = f2bf((v - mean) * rstd * ww + bb);
  }
}

// ---------------- bf16 MFMA GEMM via global_load_lds + XOR-swizzled LDS ----------------
// C = A @ B^T + bias. A[M][K], Bw[Nn][K] row-major bf16.
// LDS tiles are LINEAR [128][64] bf16 (128B rows). Swizzle (both-sides):
//   content at (row, slot16) = logical col16 = slot16 ^ (row&7)
//   staged by pre-swizzling the per-lane GLOBAL source address;
//   fragment reads apply the same XOR on the slot index.
// EPI 0: out bf16 = v + bias
// EPI 1: out bf16 = gelu(v + bias)
// EPI 2: out f32  = resid + v + bias
// EPI 3: qkv split-store: Q -> qb[bp*H+h][m][d], K -> kb[...], V -> vtb[bp*H+h][d][m]
template <int EPI>
__global__ __launch_bounds__(256) void k_gemm(const unsigned short* __restrict__ A,
                                              const unsigned short* __restrict__ Bw,
                                              const float* __restrict__ bias,
                                              const float* __restrict__ resid,
                                              unsigned short* __restrict__ outb,
                                              float* __restrict__ outf,
                                              unsigned short* __restrict__ qb,
                                              unsigned short* __restrict__ kb,
                                              unsigned short* __restrict__ vtb,
                                              int M, int Nn, int K) {
  constexpr int BM = 128, BN = 128, BK = 64;
  __shared__ unsigned short As[BM * BK];  // 16 KB, linear
  __shared__ unsigned short Bs[BN * BK];  // 16 KB, linear
  int tid = threadIdx.x;
  int lane = tid & 63, w = tid >> 6;
  int wm = w >> 1, wn = w & 1;
  int m0 = blockIdx.y * BM, n0 = blockIdx.x * BN;
  // staging geometry: 16 chunks of 1KB (8 rows x 64 cols). wave w owns chunks w*4..w*4+3.
  // lane l covers (row_in_chunk = l>>3, slot16 = l&7); source col16 = (l&7) ^ ((l>>3)&7).
  int rowc = lane >> 3;
  int csrc = (lane & 7) ^ (rowc & 7);
  int lr = lane & 15, lg = lane >> 4;
  f32x4_t acc[4][4] = {};
  for (int k0 = 0; k0 < K; k0 += BK) {
#pragma unroll
    for (int it = 0; it < 4; ++it) {
      int chunk = w * 4 + it;
      int grow = chunk * 8 + rowc;
      async_copy16(&As[chunk * 512], &A[(size_t)(m0 + grow) * K + k0 + csrc * 8]);
      async_copy16(&Bs[chunk * 512], &Bw[(size_t)(n0 + grow) * K + k0 + csrc * 8]);
    }
    __syncthreads();   // compiler emits vmcnt(0) drain before barrier -> LDS tiles ready
#pragma unroll
    for (int kk = 0; kk < BK; kk += 32) {
      int kslot = (kk >> 3) + lg;  // col16 of this fragment
      short8_t af[4], bfr[4];
#pragma unroll
      for (int i = 0; i < 4; ++i) {
        int r = wm * 64 + i * 16 + lr;
        af[i] = *(const short8_t*)&As[r * 64 + ((kslot ^ (r & 7)) * 8)];
      }
#pragma unroll
      for (int j = 0; j < 4; ++j) {
        int r = wn * 64 + j * 16 + lr;
        bfr[j] = *(const short8_t*)&Bs[r * 64 + ((kslot ^ (r & 7)) * 8)];
      }
#pragma unroll
      for (int i = 0; i < 4; ++i)
#pragma unroll
        for (int j = 0; j < 4; ++j)
          acc[i][j] = __builtin_amdgcn_mfma_f32_16x16x32_bf16(af[i], bfr[j], acc[i][j], 0, 0, 0);
    }
    __syncthreads();
  }
#pragma unroll
  for (int i = 0; i < 4; ++i)
#pragma unroll
    for (int j = 0; j < 4; ++j) {
      int col = n0 + wn * 64 + j * 16 + lr;
      float bv = bias[col];
      int row0 = m0 + wm * 64 + i * 16 + lg * 4;
      if (EPI == 3) {
        int which = col >> 9;         // 0=q 1=k 2=v (wave-uniform)
        int hh2 = (col >> 6) & 7;     // head (wave-uniform)
        int d = col & 63;
        int bp_ = row0 >> 8, m = row0 & 255;   // 4 consecutive rows stay in one bp
        size_t hb = (size_t)(bp_ * HH + hh2);
        if (which == 2) {
          short4_t pk;
#pragma unroll
          for (int r2 = 0; r2 < 4; ++r2) pk[r2] = (short)f2bf(acc[i][j][r2] + bv);
          *(short4_t*)&vtb[(hb * HD + d) * NN + m] = pk;
        } else {
          unsigned short* dst = (which == 0) ? qb : kb;
#pragma unroll
          for (int r2 = 0; r2 < 4; ++r2)
            dst[(hb * NN + m + r2) * HD + d] = f2bf(acc[i][j][r2] + bv);
        }
      } else {
#pragma unroll
        for (int r2 = 0; r2 < 4; ++r2) {
          int row = row0 + r2;
          float v = acc[i][j][r2] + bv;
          size_t off = (size_t)row * Nn + col;
          if (EPI == 0) {
            outb[off] = f2bf(v);
          } else if (EPI == 1) {
            float g = 0.5f * v * (1.f + erff(v * 0.70710678118f));
            outb[off] = f2bf(g);
          } else {
            outf[off] = resid[off] + v;
          }
        }
      }
    }
}

// ---------------- fused attention v2: no K/V LDS staging, P-only LDS, 4 blocks/CU ----------------
// grid: (4 q-tiles, H, BP); 256 threads = 4 waves; each wave owns 16 q rows independently.
__global__ __launch_bounds__(256, 4) void k_attn2(const unsigned short* __restrict__ qb,
                                                  const unsigned short* __restrict__ kb,
                                                  const unsigned short* __restrict__ vtb,
                                                  const int* __restrict__ mask,
                                                  const float* __restrict__ pos,
                                                  unsigned short* __restrict__ attn_out) {
  constexpr int LMD = NN + 8;  // 264 elems; row stride 132 words -> 2-way conflict (free)
  __shared__ unsigned short ps[64 * LMD];  // 33.75 KB
  int qt = blockIdx.x, h = blockIdx.y, bp = blockIdx.z;
  int tid = threadIdx.x, lane = tid & 63, w = tid >> 6;
  int lr = lane & 15, lg = lane >> 4;
  int q0 = qt * 64;
  size_t bh = (size_t)(bp * HH + h);
  const unsigned short* Q = qb + bh * NN * HD;
  const unsigned short* K = kb + bh * NN * HD;
  const unsigned short* VT = vtb + bh * HD * NN;
  // Q fragments direct from global (16 rows per wave)
  short8_t qf0 = *(const short8_t*)&Q[(size_t)(q0 + w * 16 + lr) * HD + lg * 8];
  short8_t qf1 = *(const short8_t*)&Q[(size_t)(q0 + w * 16 + lr) * HD + 32 + lg * 8];
  // QK^T: 16 q rows x 256 k cols
  f32x4_t sc[16] = {};
#pragma unroll
  for (int f = 0; f < 16; ++f) {
    short8_t b0 = *(const short8_t*)&K[(size_t)(f * 16 + lr) * HD + lg * 8];
    sc[f] = __builtin_amdgcn_mfma_f32_16x16x32_bf16(qf0, b0, sc[f], 0, 0, 0);
    short8_t b1 = *(const short8_t*)&K[(size_t)(f * 16 + lr) * HD + 32 + lg * 8];
    sc[f] = __builtin_amdgcn_mfma_f32_16x16x32_bf16(qf1, b1, sc[f], 0, 0, 0);
  }
  // mask + pos + softmax, rows fully resident (in place in sc)
  const float scale = 0.125f;  // 1/sqrt(64)
#pragma unroll
  for (int r2 = 0; r2 < 4; ++r2) {
    int qrow = q0 + w * 16 + lg * 4 + r2;
    const float* posp = pos + ((size_t)h * NN + qrow) * NN;
    const int* mp = mask + ((size_t)bp * NN + qrow) * NN;
    float mx = -3.0e38f;
#pragma unroll
    for (int f = 0; f < 16; ++f) {
      int col = f * 16 + lr;
      float s = (mp[col] > 0) ? (sc[f][r2] * scale + posp[col]) : -1.0e9f;
      sc[f][r2] = s;
      mx = fmaxf(mx, s);
    }
    for (int d2 = 1; d2 < 16; d2 <<= 1) mx = fmaxf(mx, __shfl_xor(mx, d2));
    float sum = 0.f;
#pragma unroll
    for (int f = 0; f < 16; ++f) { float e = __expf(sc[f][r2] - mx); sc[f][r2] = e; sum += e; }
    for (int d2 = 1; d2 < 16; d2 <<= 1) sum += __shfl_xor(sum, d2);
    float inv = 1.f / sum;
    int prow = w * 16 + lg * 4 + r2;
#pragma unroll
    for (int f = 0; f < 16; ++f) ps[prow * LMD + f * 16 + lr] = f2bf(sc[f][r2] * inv);
  }
  // P rows are wave-private: no block barrier needed (compiler orders LDS within wave)
  f32x4_t ao[4] = {};
#pragma unroll
  for (int kt = 0; kt < 8; ++kt) {
    short8_t a = *(const short8_t*)&ps[(w * 16 + lr) * LMD + kt * 32 + lg * 8];
#pragma unroll
    for (int f = 0; f < 4; ++f) {
      short8_t b = *(const short8_t*)&VT[(size_t)(f * 16 + lr) * NN + kt * 32 + lg * 8];
      ao[f] = __builtin_amdgcn_mfma_f32_16x16x32_bf16(a, b, ao[f], 0, 0, 0);
    }
  }
#pragma unroll
  for (int f = 0; f < 4; ++f)
#pragma unroll
    for (int r2 = 0; r2 < 4; ++r2) {
      int token = bp * NN + q0 + w * 16 + lg * 4 + r2;
      int d = f * 16 + lr;
      attn_out[(size_t)token * CC + h * HD + d] = f2bf(ao[f][r2]);
    }
}

extern "C" void kernel_launch(void* const* d_in, const int* in_sizes, int n_in,
                              void* d_out, int out_size, void* d_ws, size_t ws_size,
                              hipStream_t stream) {
  const float* x      = (const float*)d_in[0];
  const int*   mask   = (const int*)d_in[1];
  const float* pos    = (const float*)d_in[2];
  const float* n1w    = (const float*)d_in[3];
  const float* n1b    = (const float*)d_in[4];
  const float* qkv_w  = (const float*)d_in[5];
  const float* qkv_b  = (const float*)d_in[6];
  const float* proj_w = (const float*)d_in[7];
  const float* proj_b = (const float*)d_in[8];
  const float* n2w    = (const float*)d_in[9];
  const float* n2b    = (const float*)d_in[10];
  const float* w1     = (const float*)d_in[11];
  const float* b1     = (const float*)d_in[12];
  const float* w2     = (const float*)d_in[13];
  const float* b2     = (const float*)d_in[14];
  float* out = (float*)d_out;
  char* ws = (char*)d_ws;

  size_t off = 0;
  auto alloc = [&](size_t bytes) { size_t o = off; off += (bytes + 255) & ~(size_t)255; return o; };
  unsigned short* wqkv  = (unsigned short*)(ws + alloc((size_t)3 * CC * CC * 2));
  unsigned short* wproj = (unsigned short*)(ws + alloc((size_t)CC * CC * 2));
  unsigned short* wm1   = (unsigned short*)(ws + alloc((size_t)MLPD * CC * 2));
  unsigned short* wm2   = (unsigned short*)(ws + alloc((size_t)CC * MLPD * 2));
  unsigned short* xn    = (unsigned short*)(ws + alloc((size_t)MTOT * CC * 2));   // 32 MB
  float*          x1    = (float*)(ws + alloc((size_t)MTOT * CC * 4));            // 64 MB
  size_t region = alloc((size_t)MTOT * MLPD * 2);                                 // 128 MB shared region
  const size_t BUFE = (size_t)MTOT * CC;  // elems per 32MB buffer
  unsigned short* qbuf  = (unsigned short*)(ws + region);
  unsigned short* kbuf  = qbuf + BUFE;
  unsigned short* vtbuf = qbuf + 2 * BUFE;
  unsigned short* attnb = qbuf + 3 * BUFE;
  unsigned short* hbuf  = (unsigned short*)(ws + region);  // reuses all 4 (dead by MLP time)

  // weight conversions
  k_f2bf<<<1024, 256, 0, stream>>>(qkv_w, wqkv, 3 * CC * CC);
  k_f2bf<<<1024, 256, 0, stream>>>(proj_w, wproj, CC * CC);
  k_f2bf<<<1024, 256, 0, stream>>>(w1, wm1, MLPD * CC);
  k_f2bf<<<1024, 256, 0, stream>>>(w2, wm2, CC * MLPD);

  // norm1
  k_gn<<<BP * 2, 256, 0, stream>>>(x, n1w, n1b, xn);
  // qkv = xn @ qkv_w^T + b, split-stored into q/k/v^T head-major buffers
  k_gemm<3><<<dim3(3 * CC / 128, MTOT / 128), 256, 0, stream>>>(xn, wqkv, qkv_b, nullptr, nullptr, nullptr, qbuf, kbuf, vtbuf, MTOT, 3 * CC, CC);
  // attention
  k_attn2<<<dim3(4, HH, BP), 256, 0, stream>>>(qbuf, kbuf, vtbuf, mask, pos, attnb);
  // x1 = x + attn @ proj_w^T + proj_b
  k_gemm<2><<<dim3(CC / 128, MTOT / 128), 256, 0, stream>>>(attnb, wproj, proj_b, x, nullptr, x1, nullptr, nullptr, nullptr, MTOT, CC, CC);
  // norm2
  k_gn<<<BP * 2, 256, 0, stream>>>(x1, n2w, n2b, xn);
  // h = gelu(xn @ w1^T + b1)
  k_gemm<1><<<dim3(MLPD / 128, MTOT / 128), 256, 0, stream>>>(xn, wm1, b1, nullptr, hbuf, nullptr, nullptr, nullptr, nullptr, MTOT, MLPD, CC);
  // out = x1 + h @ w2^T + b2
  k_gemm<2><<<dim3(CC / 128, MTOT / 128), 256, 0, stream>>>(hbuf, wm2, b2, x1, nullptr, out, nullptr, nullptr, nullptr, MTOT, CC, MLPD);
}

// Round 7
// 581.789 us; speedup vs baseline: 1.6784x; 1.1556x over previous
//
#include <hip/hip_runtime.h>
#include <hip/hip_bf16.h>

// Problem constants
constexpr int BB = 2, PP = 64, NN = 256, CC = 512, HH = 8, HD = 64, MLPD = 2048;
constexpr int BP = BB * PP;       // 128
constexpr int MTOT = BP * NN;     // 32768
constexpr float EPS = 1e-5f;

typedef __attribute__((ext_vector_type(8))) short short8_t;
typedef __attribute__((ext_vector_type(4))) short short4_t;
typedef __attribute__((ext_vector_type(4))) float f32x4_t;

__device__ inline unsigned short f2bf(float f) {
  union { float f; unsigned u; } v; v.f = f;
  unsigned r = v.u + 0x7fffu + ((v.u >> 16) & 1u);
  return (unsigned short)(r >> 16);
}
__device__ inline float bf2f(unsigned short u) {
  union { unsigned u; float f; } v; v.u = ((unsigned)u) << 16;
  return v.f;
}

// async 16B global -> LDS (wave-uniform LDS base, per-lane global addr; HW writes base + lane*16)
__device__ inline void async_copy16(unsigned short* lds_base, const unsigned short* g) {
  __builtin_amdgcn_global_load_lds((const __attribute__((address_space(1))) unsigned int*)g,
                                   (__attribute__((address_space(3))) unsigned int*)lds_base,
                                   16, 0, 0);
}

// ---------------- f32 -> bf16 convert (weights) ----------------
__global__ void k_f2bf(const float* __restrict__ in, unsigned short* __restrict__ out, int n) {
  int i = blockIdx.x * blockDim.x + threadIdx.x;
  int stride = gridDim.x * blockDim.x;
  for (; i < n; i += stride) out[i] = f2bf(in[i]);
}

// ---------------- pack mask into transposed bitfield: maskT[bp][row][lr] bit f = mask[bp][row][f*16+lr]>0
__global__ void k_pack_mask(const int* __restrict__ mask, unsigned short* __restrict__ mt) {
  int idx = blockIdx.x * 256 + threadIdx.x;  // 128*256*16 = 524288
  int lr = idx & 15;
  int row = (idx >> 4) & 255;
  int bp = idx >> 12;
  const int* mp = mask + ((size_t)bp * NN + row) * NN;
  unsigned v = 0;
#pragma unroll
  for (int f = 0; f < 16; ++f) v |= (unsigned)(mp[f * 16 + lr] > 0) << f;
  mt[idx] = (unsigned short)v;
}

// ---------------- pack pos transposed bf16: posT[((h*256+row)*16+lr)*16+f] = pos[h][row][f*16+lr]
__global__ void k_pack_pos(const float* __restrict__ pos, unsigned short* __restrict__ pt) {
  int idx = blockIdx.x * 256 + threadIdx.x;  // 8*256*256 = 524288
  int f = idx & 15;
  int lr = (idx >> 4) & 15;
  int row = (idx >> 8) & 255;
  int h = idx >> 16;
  pt[idx] = f2bf(pos[((size_t)h * NN + row) * NN + f * 16 + lr]);
}

// ---------------- group norm over N (tokens), per (bp, c) ----------------
__global__ void k_gn(const float* __restrict__ x, const float* __restrict__ w,
                     const float* __restrict__ b, unsigned short* __restrict__ out) {
  int bp = blockIdx.x >> 1;
  int c = ((blockIdx.x & 1) << 8) + threadIdx.x;
  const float* xp = x + (size_t)bp * NN * CC + c;
  float s = 0.f, sq = 0.f;
  for (int n = 0; n < NN; ++n) { float v = xp[(size_t)n * CC]; s += v; sq += v * v; }
  float mean = s * (1.f / NN);
  float var = sq * (1.f / NN) - mean * mean;
  float rstd = rsqrtf(var + EPS);
  float ww = w[c], bb = b[c];
  unsigned short* op = out + (size_t)bp * NN * CC + c;
  for (int n = 0; n < NN; ++n) {
    float v = xp[(size_t)n * CC];
    op[(size_t)n * CC] = f2bf((v - mean) * rstd * ww + bb);
  }
}

// ---------------- bf16 MFMA GEMM via global_load_lds + XOR-swizzled LDS ----------------
// C = A @ B^T + bias. A[M][K], Bw[Nn][K] row-major bf16.
// EPI 0: out bf16 = v + bias
// EPI 1: out bf16 = gelu(v + bias)
// EPI 2: out f32  = resid + v + bias
// EPI 3: qkv split-store: Q(*0.125) -> qb[bp*H+h][m][d], K -> kb, V -> vtb[bp*H+h][d][m]
template <int EPI>
__global__ __launch_bounds__(256) void k_gemm(const unsigned short* __restrict__ A,
                                              const unsigned short* __restrict__ Bw,
                                              const float* __restrict__ bias,
                                              const float* __restrict__ resid,
                                              unsigned short* __restrict__ outb,
                                              float* __restrict__ outf,
                                              unsigned short* __restrict__ qb,
                                              unsigned short* __restrict__ kb,
                                              unsigned short* __restrict__ vtb,
                                              int M, int Nn, int K) {
  constexpr int BM = 128, BN = 128, BK = 64;
  __shared__ unsigned short As[BM * BK];  // 16 KB, linear
  __shared__ unsigned short Bs[BN * BK];  // 16 KB, linear
  int tid = threadIdx.x;
  int lane = tid & 63, w = tid >> 6;
  int wm = w >> 1, wn = w & 1;
  int m0 = blockIdx.y * BM, n0 = blockIdx.x * BN;
  int rowc = lane >> 3;
  int csrc = (lane & 7) ^ (rowc & 7);
  int lr = lane & 15, lg = lane >> 4;
  f32x4_t acc[4][4] = {};
  for (int k0 = 0; k0 < K; k0 += BK) {
#pragma unroll
    for (int it = 0; it < 4; ++it) {
      int chunk = w * 4 + it;
      int grow = chunk * 8 + rowc;
      async_copy16(&As[chunk * 512], &A[(size_t)(m0 + grow) * K + k0 + csrc * 8]);
      async_copy16(&Bs[chunk * 512], &Bw[(size_t)(n0 + grow) * K + k0 + csrc * 8]);
    }
    __syncthreads();
#pragma unroll
    for (int kk = 0; kk < BK; kk += 32) {
      int kslot = (kk >> 3) + lg;
      short8_t af[4], bfr[4];
#pragma unroll
      for (int i = 0; i < 4; ++i) {
        int r = wm * 64 + i * 16 + lr;
        af[i] = *(const short8_t*)&As[r * 64 + ((kslot ^ (r & 7)) * 8)];
      }
#pragma unroll
      for (int j = 0; j < 4; ++j) {
        int r = wn * 64 + j * 16 + lr;
        bfr[j] = *(const short8_t*)&Bs[r * 64 + ((kslot ^ (r & 7)) * 8)];
      }
#pragma unroll
      for (int i = 0; i < 4; ++i)
#pragma unroll
        for (int j = 0; j < 4; ++j)
          acc[i][j] = __builtin_amdgcn_mfma_f32_16x16x32_bf16(af[i], bfr[j], acc[i][j], 0, 0, 0);
    }
    __syncthreads();
  }
#pragma unroll
  for (int i = 0; i < 4; ++i)
#pragma unroll
    for (int j = 0; j < 4; ++j) {
      int col = n0 + wn * 64 + j * 16 + lr;
      float bv = bias[col];
      int row0 = m0 + wm * 64 + i * 16 + lg * 4;
      if (EPI == 3) {
        int which = col >> 9;         // 0=q 1=k 2=v (wave-uniform)
        int hh2 = (col >> 6) & 7;     // head (wave-uniform)
        int d = col & 63;
        int bp_ = row0 >> 8, m = row0 & 255;
        size_t hb = (size_t)(bp_ * HH + hh2);
        if (which == 2) {
          short4_t pk;
#pragma unroll
          for (int r2 = 0; r2 < 4; ++r2) pk[r2] = (short)f2bf(acc[i][j][r2] + bv);
          *(short4_t*)&vtb[(hb * HD + d) * NN + m] = pk;
        } else if (which == 0) {
#pragma unroll
          for (int r2 = 0; r2 < 4; ++r2)
            qb[(hb * NN + m + r2) * HD + d] = f2bf((acc[i][j][r2] + bv) * 0.125f);
        } else {
#pragma unroll
          for (int r2 = 0; r2 < 4; ++r2)
            kb[(hb * NN + m + r2) * HD + d] = f2bf(acc[i][j][r2] + bv);
        }
      } else {
#pragma unroll
        for (int r2 = 0; r2 < 4; ++r2) {
          int row = row0 + r2;
          float v = acc[i][j][r2] + bv;
          size_t off = (size_t)row * Nn + col;
          if (EPI == 0) {
            outb[off] = f2bf(v);
          } else if (EPI == 1) {
            float g = 0.5f * v * (1.f + erff(v * 0.70710678118f));
            outb[off] = f2bf(g);
          } else {
            outf[off] = resid[off] + v;
          }
        }
      }
    }
}

// ---------------- fused attention v3: packed maskT/posT, scale pre-folded into Q ----------------
// grid: (4 q-tiles, H, BP); 256 threads = 4 waves; each wave owns 16 q rows independently.
__global__ __launch_bounds__(256, 4) void k_attn3(const unsigned short* __restrict__ qb,
                                                  const unsigned short* __restrict__ kb,
                                                  const unsigned short* __restrict__ vtb,
                                                  const unsigned short* __restrict__ maskT,
                                                  const unsigned short* __restrict__ posT,
                                                  unsigned short* __restrict__ attn_out) {
  constexpr int LMD = NN + 8;  // 264 elems; 2-way bank conflict (free)
  __shared__ unsigned short ps[64 * LMD];  // 33.75 KB
  int qt = blockIdx.x, h = blockIdx.y, bp = blockIdx.z;
  int tid = threadIdx.x, lane = tid & 63, w = tid >> 6;
  int lr = lane & 15, lg = lane >> 4;
  int q0 = qt * 64;
  size_t bh = (size_t)(bp * HH + h);
  const unsigned short* Q = qb + bh * NN * HD;
  const unsigned short* K = kb + bh * NN * HD;
  const unsigned short* VT = vtb + bh * HD * NN;
  short8_t qf0 = *(const short8_t*)&Q[(size_t)(q0 + w * 16 + lr) * HD + lg * 8];
  short8_t qf1 = *(const short8_t*)&Q[(size_t)(q0 + w * 16 + lr) * HD + 32 + lg * 8];
  // prefetch packed mask/pos for this wave's 4 rows (independent of MFMA results)
  unsigned mbits[4];
  short8_t pv0[4], pv1[4];
#pragma unroll
  for (int r2 = 0; r2 < 4; ++r2) {
    int qrow = q0 + w * 16 + lg * 4 + r2;
    mbits[r2] = maskT[((size_t)bp * NN + qrow) * 16 + lr];
    const unsigned short* pp = &posT[(((size_t)h * NN + qrow) * 16 + lr) * 16];
    pv0[r2] = *(const short8_t*)&pp[0];
    pv1[r2] = *(const short8_t*)&pp[8];
  }
  // QK^T: 16 q rows x 256 k cols
  f32x4_t sc[16] = {};
#pragma unroll
  for (int f = 0; f < 16; ++f) {
    short8_t b0 = *(const short8_t*)&K[(size_t)(f * 16 + lr) * HD + lg * 8];
    sc[f] = __builtin_amdgcn_mfma_f32_16x16x32_bf16(qf0, b0, sc[f], 0, 0, 0);
    short8_t b1 = *(const short8_t*)&K[(size_t)(f * 16 + lr) * HD + 32 + lg * 8];
    sc[f] = __builtin_amdgcn_mfma_f32_16x16x32_bf16(qf1, b1, sc[f], 0, 0, 0);
  }
  // mask + pos + softmax (scale already folded into Q)
#pragma unroll
  for (int r2 = 0; r2 < 4; ++r2) {
    float mx = -3.0e38f;
#pragma unroll
    for (int f = 0; f < 16; ++f) {
      float pw = bf2f((unsigned short)((f < 8) ? pv0[r2][f] : pv1[r2][f - 8]));
      float s = ((mbits[r2] >> f) & 1) ? (sc[f][r2] + pw) : -1.0e9f;
      sc[f][r2] = s;
      mx = fmaxf(mx, s);
    }
    for (int d2 = 1; d2 < 16; d2 <<= 1) mx = fmaxf(mx, __shfl_xor(mx, d2));
    float sum = 0.f;
#pragma unroll
    for (int f = 0; f < 16; ++f) { float e = __expf(sc[f][r2] - mx); sc[f][r2] = e; sum += e; }
    for (int d2 = 1; d2 < 16; d2 <<= 1) sum += __shfl_xor(sum, d2);
    float inv = 1.f / sum;
    int prow = w * 16 + lg * 4 + r2;
#pragma unroll
    for (int f = 0; f < 16; ++f) ps[prow * LMD + f * 16 + lr] = f2bf(sc[f][r2] * inv);
  }
  // P rows are wave-private: no block barrier needed
  f32x4_t ao[4] = {};
#pragma unroll
  for (int kt = 0; kt < 8; ++kt) {
    short8_t a = *(const short8_t*)&ps[(w * 16 + lr) * LMD + kt * 32 + lg * 8];
#pragma unroll
    for (int f = 0; f < 4; ++f) {
      short8_t b = *(const short8_t*)&VT[(size_t)(f * 16 + lr) * NN + kt * 32 + lg * 8];
      ao[f] = __builtin_amdgcn_mfma_f32_16x16x32_bf16(a, b, ao[f], 0, 0, 0);
    }
  }
#pragma unroll
  for (int f = 0; f < 4; ++f)
#pragma unroll
    for (int r2 = 0; r2 < 4; ++r2) {
      int token = bp * NN + q0 + w * 16 + lg * 4 + r2;
      int d = f * 16 + lr;
      attn_out[(size_t)token * CC + h * HD + d] = f2bf(ao[f][r2]);
    }
}

extern "C" void kernel_launch(void* const* d_in, const int* in_sizes, int n_in,
                              void* d_out, int out_size, void* d_ws, size_t ws_size,
                              hipStream_t stream) {
  const float* x      = (const float*)d_in[0];
  const int*   mask   = (const int*)d_in[1];
  const float* pos    = (const float*)d_in[2];
  const float* n1w    = (const float*)d_in[3];
  const float* n1b    = (const float*)d_in[4];
  const float* qkv_w  = (const float*)d_in[5];
  const float* qkv_b  = (const float*)d_in[6];
  const float* proj_w = (const float*)d_in[7];
  const float* proj_b = (const float*)d_in[8];
  const float* n2w    = (const float*)d_in[9];
  const float* n2b    = (const float*)d_in[10];
  const float* w1     = (const float*)d_in[11];
  const float* b1     = (const float*)d_in[12];
  const float* w2     = (const float*)d_in[13];
  const float* b2     = (const float*)d_in[14];
  float* out = (float*)d_out;
  char* ws = (char*)d_ws;

  size_t off = 0;
  auto alloc = [&](size_t bytes) { size_t o = off; off += (bytes + 255) & ~(size_t)255; return o; };
  unsigned short* wqkv  = (unsigned short*)(ws + alloc((size_t)3 * CC * CC * 2));
  unsigned short* wproj = (unsigned short*)(ws + alloc((size_t)CC * CC * 2));
  unsigned short* wm1   = (unsigned short*)(ws + alloc((size_t)MLPD * CC * 2));
  unsigned short* wm2   = (unsigned short*)(ws + alloc((size_t)CC * MLPD * 2));
  unsigned short* maskT = (unsigned short*)(ws + alloc((size_t)BP * NN * 16 * 2));     // 1 MB
  unsigned short* posT  = (unsigned short*)(ws + alloc((size_t)HH * NN * NN * 2));     // 1 MB
  unsigned short* xn    = (unsigned short*)(ws + alloc((size_t)MTOT * CC * 2));   // 32 MB
  float*          x1    = (float*)(ws + alloc((size_t)MTOT * CC * 4));            // 64 MB
  size_t region = alloc((size_t)MTOT * MLPD * 2);                                 // 128 MB shared region
  const size_t BUFE = (size_t)MTOT * CC;  // elems per 32MB buffer
  unsigned short* qbuf  = (unsigned short*)(ws + region);
  unsigned short* kbuf  = qbuf + BUFE;
  unsigned short* vtbuf = qbuf + 2 * BUFE;
  unsigned short* attnb = qbuf + 3 * BUFE;
  unsigned short* hbuf  = (unsigned short*)(ws + region);  // reuses all 4 (dead by MLP time)

  // weight conversions + packs
  k_f2bf<<<1024, 256, 0, stream>>>(qkv_w, wqkv, 3 * CC * CC);
  k_f2bf<<<1024, 256, 0, stream>>>(proj_w, wproj, CC * CC);
  k_f2bf<<<1024, 256, 0, stream>>>(w1, wm1, MLPD * CC);
  k_f2bf<<<1024, 256, 0, stream>>>(w2, wm2, CC * MLPD);
  k_pack_mask<<<2048, 256, 0, stream>>>(mask, maskT);
  k_pack_pos<<<2048, 256, 0, stream>>>(pos, posT);

  // norm1
  k_gn<<<BP * 2, 256, 0, stream>>>(x, n1w, n1b, xn);
  // qkv = xn @ qkv_w^T + b, split-stored into q(*scale)/k/v^T head-major buffers
  k_gemm<3><<<dim3(3 * CC / 128, MTOT / 128), 256, 0, stream>>>(xn, wqkv, qkv_b, nullptr, nullptr, nullptr, qbuf, kbuf, vtbuf, MTOT, 3 * CC, CC);
  // attention
  k_attn3<<<dim3(4, HH, BP), 256, 0, stream>>>(qbuf, kbuf, vtbuf, maskT, posT, attnb);
  // x1 = x + attn @ proj_w^T + proj_b
  k_gemm<2><<<dim3(CC / 128, MTOT / 128), 256, 0, stream>>>(attnb, wproj, proj_b, x, nullptr, x1, nullptr, nullptr, nullptr, MTOT, CC, CC);
  // norm2
  k_gn<<<BP * 2, 256, 0, stream>>>(x1, n2w, n2b, xn);
  // h = gelu(xn @ w1^T + b1)
  k_gemm<1><<<dim3(MLPD / 128, MTOT / 128), 256, 0, stream>>>(xn, wm1, b1, nullptr, hbuf, nullptr, nullptr, nullptr, nullptr, MTOT, MLPD, CC);
  // out = x1 + h @ w2^T + b2
  k_gemm<2><<<dim3(CC / 128, MTOT / 128), 256, 0, stream>>>(hbuf, wm2, b2, x1, nullptr, out, nullptr, nullptr, nullptr, MTOT, CC, MLPD);
}

// Round 8
// 569.601 us; speedup vs baseline: 1.7143x; 1.0214x over previous
//
#include <hip/hip_runtime.h>
#include <hip/hip_bf16.h>

// Problem constants
constexpr int BB = 2, PP = 64, NN = 256, CC = 512, HH = 8, HD = 64, MLPD = 2048;
constexpr int BP = BB * PP;       // 128
constexpr int MTOT = BP * NN;     // 32768
constexpr float EPS = 1e-5f;

typedef __attribute__((ext_vector_type(8))) short short8_t;
typedef __attribute__((ext_vector_type(4))) short short4_t;
typedef __attribute__((ext_vector_type(4))) float f32x4_t;

__device__ inline unsigned short f2bf(float f) {
  union { float f; unsigned u; } v; v.f = f;
  unsigned r = v.u + 0x7fffu + ((v.u >> 16) & 1u);
  return (unsigned short)(r >> 16);
}
__device__ inline float bf2f(unsigned short u) {
  union { unsigned u; float f; } v; v.u = ((unsigned)u) << 16;
  return v.f;
}

// async 16B global -> LDS (wave-uniform LDS base, per-lane global addr; HW writes base + lane*16)
__device__ inline void async_copy16(unsigned short* lds_base, const unsigned short* g) {
  __builtin_amdgcn_global_load_lds((const __attribute__((address_space(1))) unsigned int*)g,
                                   (__attribute__((address_space(3))) unsigned int*)lds_base,
                                   16, 0, 0);
}

// cheap exact-enough gelu: tanh form, err<~5e-4 abs (bf16 output)
__device__ inline float gelu_fast(float v) {
  float vc = fminf(fmaxf(v, -8.f), 8.f);
  float e = __expf(1.5957691216f * vc + 0.071354816f * vc * vc * vc);
  return v * e * __builtin_amdgcn_rcpf(e + 1.f);
}

// ---------------- f32 -> bf16 convert (weights) ----------------
__global__ void k_f2bf(const float* __restrict__ in, unsigned short* __restrict__ out, int n) {
  int i = blockIdx.x * blockDim.x + threadIdx.x;
  int stride = gridDim.x * blockDim.x;
  for (; i < n; i += stride) out[i] = f2bf(in[i]);
}

// ---------------- pack mask into transposed bitfield: maskT[bp][row][lr] bit f = mask[bp][row][f*16+lr]>0
__global__ void k_pack_mask(const int* __restrict__ mask, unsigned short* __restrict__ mt) {
  int idx = blockIdx.x * 256 + threadIdx.x;  // 128*256*16 = 524288
  int lr = idx & 15;
  int row = (idx >> 4) & 255;
  int bp = idx >> 12;
  const int* mp = mask + ((size_t)bp * NN + row) * NN;
  unsigned v = 0;
#pragma unroll
  for (int f = 0; f < 16; ++f) v |= (unsigned)(mp[f * 16 + lr] > 0) << f;
  mt[idx] = (unsigned short)v;
}

// ---------------- pack pos transposed bf16: posT[((h*256+row)*16+lr)*16+f] = pos[h][row][f*16+lr]
__global__ void k_pack_pos(const float* __restrict__ pos, unsigned short* __restrict__ pt) {
  int idx = blockIdx.x * 256 + threadIdx.x;  // 8*256*256 = 524288
  int f = idx & 15;
  int lr = (idx >> 4) & 15;
  int row = (idx >> 8) & 255;
  int h = idx >> 16;
  pt[idx] = f2bf(pos[((size_t)h * NN + row) * NN + f * 16 + lr]);
}

// ---------------- group norm over N (tokens), per (bp, c) ----------------
__global__ void k_gn(const float* __restrict__ x, const float* __restrict__ w,
                     const float* __restrict__ b, unsigned short* __restrict__ out) {
  int bp = blockIdx.x >> 1;
  int c = ((blockIdx.x & 1) << 8) + threadIdx.x;
  const float* xp = x + (size_t)bp * NN * CC + c;
  float s = 0.f, sq = 0.f;
  for (int n = 0; n < NN; ++n) { float v = xp[(size_t)n * CC]; s += v; sq += v * v; }
  float mean = s * (1.f / NN);
  float var = sq * (1.f / NN) - mean * mean;
  float rstd = rsqrtf(var + EPS);
  float ww = w[c], bb = b[c];
  unsigned short* op = out + (size_t)bp * NN * CC + c;
  for (int n = 0; n < NN; ++n) {
    float v = xp[(size_t)n * CC];
    op[(size_t)n * CC] = f2bf((v - mean) * rstd * ww + bb);
  }
}

// ---------------- bf16 MFMA GEMM: gload_lds + XOR swizzle + 2-phase double-buffered K-loop ----
// C = A @ B^T + bias. A[M][K], Bw[Nn][K] row-major bf16.
// EPI 0: out bf16 = v + bias
// EPI 1: out bf16 = gelu(v + bias)
// EPI 2: out f32  = resid + v + bias
// EPI 3: qkv split-store: Q(*0.125) -> qb[bp*H+h][m][d], K -> kb, V -> vtb[bp*H+h][d][m]
template <int EPI>
__global__ __launch_bounds__(256) void k_gemm(const unsigned short* __restrict__ A,
                                              const unsigned short* __restrict__ Bw,
                                              const float* __restrict__ bias,
                                              const float* __restrict__ resid,
                                              unsigned short* __restrict__ outb,
                                              float* __restrict__ outf,
                                              unsigned short* __restrict__ qb,
                                              unsigned short* __restrict__ kb,
                                              unsigned short* __restrict__ vtb,
                                              int M, int Nn, int K) {
  constexpr int BM = 128, BN = 128, BK = 64;
  __shared__ unsigned short As[2][BM * BK];  // 2 x 16 KB
  __shared__ unsigned short Bs[2][BN * BK];  // 2 x 16 KB
  int tid = threadIdx.x;
  int lane = tid & 63, w = tid >> 6;
  int wm = w >> 1, wn = w & 1;
  int m0 = blockIdx.y * BM, n0 = blockIdx.x * BN;
  int rowc = lane >> 3;
  int csrc = (lane & 7) ^ (rowc & 7);
  int lr = lane & 15, lg = lane >> 4;
  f32x4_t acc[4][4] = {};

  auto STAGE = [&](int buf, int k0) {
#pragma unroll
    for (int it = 0; it < 4; ++it) {
      int chunk = w * 4 + it;
      int grow = chunk * 8 + rowc;
      async_copy16(&As[buf][chunk * 512], &A[(size_t)(m0 + grow) * K + k0 + csrc * 8]);
      async_copy16(&Bs[buf][chunk * 512], &Bw[(size_t)(n0 + grow) * K + k0 + csrc * 8]);
    }
  };

  const int nt = K / BK;
  STAGE(0, 0);
  __syncthreads();                     // drain prologue loads
  for (int t = 0; t < nt; ++t) {
    int cur = t & 1;
    if (t + 1 < nt) STAGE(cur ^ 1, (t + 1) * BK);  // issue next tile BEFORE compute
#pragma unroll
    for (int kk = 0; kk < BK; kk += 32) {
      int kslot = (kk >> 3) + lg;
      short8_t af[4], bfr[4];
#pragma unroll
      for (int i = 0; i < 4; ++i) {
        int r = wm * 64 + i * 16 + lr;
        af[i] = *(const short8_t*)&As[cur][r * 64 + ((kslot ^ (r & 7)) * 8)];
      }
#pragma unroll
      for (int j = 0; j < 4; ++j) {
        int r = wn * 64 + j * 16 + lr;
        bfr[j] = *(const short8_t*)&Bs[cur][r * 64 + ((kslot ^ (r & 7)) * 8)];
      }
#pragma unroll
      for (int i = 0; i < 4; ++i)
#pragma unroll
        for (int j = 0; j < 4; ++j)
          acc[i][j] = __builtin_amdgcn_mfma_f32_16x16x32_bf16(af[i], bfr[j], acc[i][j], 0, 0, 0);
    }
    __syncthreads();  // drains next-tile loads; ensures cur-buf reads done before overwrite
  }
#pragma unroll
  for (int i = 0; i < 4; ++i)
#pragma unroll
    for (int j = 0; j < 4; ++j) {
      int col = n0 + wn * 64 + j * 16 + lr;
      float bv = bias[col];
      int row0 = m0 + wm * 64 + i * 16 + lg * 4;
      if (EPI == 3) {
        int which = col >> 9;         // 0=q 1=k 2=v (wave-uniform)
        int hh2 = (col >> 6) & 7;     // head (wave-uniform)
        int d = col & 63;
        int bp_ = row0 >> 8, m = row0 & 255;
        size_t hb = (size_t)(bp_ * HH + hh2);
        if (which == 2) {
          short4_t pk;
#pragma unroll
          for (int r2 = 0; r2 < 4; ++r2) pk[r2] = (short)f2bf(acc[i][j][r2] + bv);
          *(short4_t*)&vtb[(hb * HD + d) * NN + m] = pk;
        } else if (which == 0) {
#pragma unroll
          for (int r2 = 0; r2 < 4; ++r2)
            qb[(hb * NN + m + r2) * HD + d] = f2bf((acc[i][j][r2] + bv) * 0.125f);
        } else {
#pragma unroll
          for (int r2 = 0; r2 < 4; ++r2)
            kb[(hb * NN + m + r2) * HD + d] = f2bf(acc[i][j][r2] + bv);
        }
      } else {
#pragma unroll
        for (int r2 = 0; r2 < 4; ++r2) {
          int row = row0 + r2;
          float v = acc[i][j][r2] + bv;
          size_t off = (size_t)row * Nn + col;
          if (EPI == 0) {
            outb[off] = f2bf(v);
          } else if (EPI == 1) {
            outb[off] = f2bf(gelu_fast(v));
          } else {
            outf[off] = resid[off] + v;
          }
        }
      }
    }
}

// ---------------- fused attention v3: packed maskT/posT, scale pre-folded into Q ----------------
// grid: (4 q-tiles, H, BP); 256 threads = 4 waves; each wave owns 16 q rows independently.
__global__ __launch_bounds__(256, 4) void k_attn3(const unsigned short* __restrict__ qb,
                                                  const unsigned short* __restrict__ kb,
                                                  const unsigned short* __restrict__ vtb,
                                                  const unsigned short* __restrict__ maskT,
                                                  const unsigned short* __restrict__ posT,
                                                  unsigned short* __restrict__ attn_out) {
  constexpr int LMD = NN + 8;  // 264 elems; 2-way bank conflict (free)
  __shared__ unsigned short ps[64 * LMD];  // 33.75 KB
  int qt = blockIdx.x, h = blockIdx.y, bp = blockIdx.z;
  int tid = threadIdx.x, lane = tid & 63, w = tid >> 6;
  int lr = lane & 15, lg = lane >> 4;
  int q0 = qt * 64;
  size_t bh = (size_t)(bp * HH + h);
  const unsigned short* Q = qb + bh * NN * HD;
  const unsigned short* K = kb + bh * NN * HD;
  const unsigned short* VT = vtb + bh * HD * NN;
  short8_t qf0 = *(const short8_t*)&Q[(size_t)(q0 + w * 16 + lr) * HD + lg * 8];
  short8_t qf1 = *(const short8_t*)&Q[(size_t)(q0 + w * 16 + lr) * HD + 32 + lg * 8];
  // prefetch packed mask/pos for this wave's 4 rows (independent of MFMA results)
  unsigned mbits[4];
  short8_t pv0[4], pv1[4];
#pragma unroll
  for (int r2 = 0; r2 < 4; ++r2) {
    int qrow = q0 + w * 16 + lg * 4 + r2;
    mbits[r2] = maskT[((size_t)bp * NN + qrow) * 16 + lr];
    const unsigned short* pp = &posT[(((size_t)h * NN + qrow) * 16 + lr) * 16];
    pv0[r2] = *(const short8_t*)&pp[0];
    pv1[r2] = *(const short8_t*)&pp[8];
  }
  // QK^T: 16 q rows x 256 k cols
  f32x4_t sc[16] = {};
#pragma unroll
  for (int f = 0; f < 16; ++f) {
    short8_t b0 = *(const short8_t*)&K[(size_t)(f * 16 + lr) * HD + lg * 8];
    sc[f] = __builtin_amdgcn_mfma_f32_16x16x32_bf16(qf0, b0, sc[f], 0, 0, 0);
    short8_t b1 = *(const short8_t*)&K[(size_t)(f * 16 + lr) * HD + 32 + lg * 8];
    sc[f] = __builtin_amdgcn_mfma_f32_16x16x32_bf16(qf1, b1, sc[f], 0, 0, 0);
  }
  // mask + pos + softmax (scale already folded into Q)
#pragma unroll
  for (int r2 = 0; r2 < 4; ++r2) {
    float mx = -3.0e38f;
#pragma unroll
    for (int f = 0; f < 16; ++f) {
      float pw = bf2f((unsigned short)((f < 8) ? pv0[r2][f] : pv1[r2][f - 8]));
      float s = ((mbits[r2] >> f) & 1) ? (sc[f][r2] + pw) : -1.0e9f;
      sc[f][r2] = s;
      mx = fmaxf(mx, s);
    }
    for (int d2 = 1; d2 < 16; d2 <<= 1) mx = fmaxf(mx, __shfl_xor(mx, d2));
    float sum = 0.f;
#pragma unroll
    for (int f = 0; f < 16; ++f) { float e = __expf(sc[f][r2] - mx); sc[f][r2] = e; sum += e; }
    for (int d2 = 1; d2 < 16; d2 <<= 1) sum += __shfl_xor(sum, d2);
    float inv = 1.f / sum;
    int prow = w * 16 + lg * 4 + r2;
#pragma unroll
    for (int f = 0; f < 16; ++f) ps[prow * LMD + f * 16 + lr] = f2bf(sc[f][r2] * inv);
  }
  // P rows are wave-private: no block barrier needed
  f32x4_t ao[4] = {};
#pragma unroll
  for (int kt = 0; kt < 8; ++kt) {
    short8_t a = *(const short8_t*)&ps[(w * 16 + lr) * LMD + kt * 32 + lg * 8];
#pragma unroll
    for (int f = 0; f < 4; ++f) {
      short8_t b = *(const short8_t*)&VT[(size_t)(f * 16 + lr) * NN + kt * 32 + lg * 8];
      ao[f] = __builtin_amdgcn_mfma_f32_16x16x32_bf16(a, b, ao[f], 0, 0, 0);
    }
  }
#pragma unroll
  for (int f = 0; f < 4; ++f)
#pragma unroll
    for (int r2 = 0; r2 < 4; ++r2) {
      int token = bp * NN + q0 + w * 16 + lg * 4 + r2;
      int d = f * 16 + lr;
      attn_out[(size_t)token * CC + h * HD + d] = f2bf(ao[f][r2]);
    }
}

extern "C" void kernel_launch(void* const* d_in, const int* in_sizes, int n_in,
                              void* d_out, int out_size, void* d_ws, size_t ws_size,
                              hipStream_t stream) {
  const float* x      = (const float*)d_in[0];
  const int*   mask   = (const int*)d_in[1];
  const float* pos    = (const float*)d_in[2];
  const float* n1w    = (const float*)d_in[3];
  const float* n1b    = (const float*)d_in[4];
  const float* qkv_w  = (const float*)d_in[5];
  const float* qkv_b  = (const float*)d_in[6];
  const float* proj_w = (const float*)d_in[7];
  const float* proj_b = (const float*)d_in[8];
  const float* n2w    = (const float*)d_in[9];
  const float* n2b    = (const float*)d_in[10];
  const float* w1     = (const float*)d_in[11];
  const float* b1     = (const float*)d_in[12];
  const float* w2     = (const float*)d_in[13];
  const float* b2     = (const float*)d_in[14];
  float* out = (float*)d_out;
  char* ws = (char*)d_ws;

  size_t off = 0;
  auto alloc = [&](size_t bytes) { size_t o = off; off += (bytes + 255) & ~(size_t)255; return o; };
  unsigned short* wqkv  = (unsigned short*)(ws + alloc((size_t)3 * CC * CC * 2));
  unsigned short* wproj = (unsigned short*)(ws + alloc((size_t)CC * CC * 2));
  unsigned short* wm1   = (unsigned short*)(ws + alloc((size_t)MLPD * CC * 2));
  unsigned short* wm2   = (unsigned short*)(ws + alloc((size_t)CC * MLPD * 2));
  unsigned short* maskT = (unsigned short*)(ws + alloc((size_t)BP * NN * 16 * 2));     // 1 MB
  unsigned short* posT  = (unsigned short*)(ws + alloc((size_t)HH * NN * NN * 2));     // 1 MB
  unsigned short* xn    = (unsigned short*)(ws + alloc((size_t)MTOT * CC * 2));   // 32 MB
  float*          x1    = (float*)(ws + alloc((size_t)MTOT * CC * 4));            // 64 MB
  size_t region = alloc((size_t)MTOT * MLPD * 2);                                 // 128 MB shared region
  const size_t BUFE = (size_t)MTOT * CC;  // elems per 32MB buffer
  unsigned short* qbuf  = (unsigned short*)(ws + region);
  unsigned short* kbuf  = qbuf + BUFE;
  unsigned short* vtbuf = qbuf + 2 * BUFE;
  unsigned short* attnb = qbuf + 3 * BUFE;
  unsigned short* hbuf  = (unsigned short*)(ws + region);  // reuses all 4 (dead by MLP time)

  // weight conversions + packs
  k_f2bf<<<1024, 256, 0, stream>>>(qkv_w, wqkv, 3 * CC * CC);
  k_f2bf<<<1024, 256, 0, stream>>>(proj_w, wproj, CC * CC);
  k_f2bf<<<1024, 256, 0, stream>>>(w1, wm1, MLPD * CC);
  k_f2bf<<<1024, 256, 0, stream>>>(w2, wm2, CC * MLPD);
  k_pack_mask<<<2048, 256, 0, stream>>>(mask, maskT);
  k_pack_pos<<<2048, 256, 0, stream>>>(pos, posT);

  // norm1
  k_gn<<<BP * 2, 256, 0, stream>>>(x, n1w, n1b, xn);
  // qkv = xn @ qkv_w^T + b, split-stored into q(*scale)/k/v^T head-major buffers
  k_gemm<3><<<dim3(3 * CC / 128, MTOT / 128), 256, 0, stream>>>(xn, wqkv, qkv_b, nullptr, nullptr, nullptr, qbuf, kbuf, vtbuf, MTOT, 3 * CC, CC);
  // attention
  k_attn3<<<dim3(4, HH, BP), 256, 0, stream>>>(qbuf, kbuf, vtbuf, maskT, posT, attnb);
  // x1 = x + attn @ proj_w^T + proj_b
  k_gemm<2><<<dim3(CC / 128, MTOT / 128), 256, 0, stream>>>(attnb, wproj, proj_b, x, nullptr, x1, nullptr, nullptr, nullptr, MTOT, CC, CC);
  // norm2
  k_gn<<<BP * 2, 256, 0, stream>>>(x1, n2w, n2b, xn);
  // h = gelu(xn @ w1^T + b1)
  k_gemm<1><<<dim3(MLPD / 128, MTOT / 128), 256, 0, stream>>>(xn, wm1, b1, nullptr, hbuf, nullptr, nullptr, nullptr, nullptr, MTOT, MLPD, CC);
  // out = x1 + h @ w2^T + b2
  k_gemm<2><<<dim3(CC / 128, MTOT / 128), 256, 0, stream>>>(hbuf, wm2, b2, x1, nullptr, out, nullptr, nullptr, nullptr, MTOT, CC, MLPD);
}

// Round 9
// 527.978 us; speedup vs baseline: 1.8495x; 1.0788x over previous
//
#include <hip/hip_runtime.h>
#include <hip/hip_bf16.h>

// Problem constants
constexpr int BB = 2, PP = 64, NN = 256, CC = 512, HH = 8, HD = 64, MLPD = 2048;
constexpr int BP = BB * PP;       // 128
constexpr int MTOT = BP * NN;     // 32768
constexpr float EPS = 1e-5f;

typedef __attribute__((ext_vector_type(8))) short short8_t;
typedef __attribute__((ext_vector_type(4))) short short4_t;
typedef __attribute__((ext_vector_type(4))) float f32x4_t;

__device__ inline unsigned short f2bf(float f) {
  union { float f; unsigned u; } v; v.f = f;
  unsigned r = v.u + 0x7fffu + ((v.u >> 16) & 1u);
  return (unsigned short)(r >> 16);
}
__device__ inline float bf2f(unsigned short u) {
  union { unsigned u; float f; } v; v.u = ((unsigned)u) << 16;
  return v.f;
}

// async 16B global -> LDS (wave-uniform LDS base, per-lane global addr; HW writes base + lane*16)
__device__ inline void async_copy16(unsigned short* lds_base, const unsigned short* g) {
  __builtin_amdgcn_global_load_lds((const __attribute__((address_space(1))) unsigned int*)g,
                                   (__attribute__((address_space(3))) unsigned int*)lds_base,
                                   16, 0, 0);
}

// cheap exact-enough gelu: tanh form, err<~5e-4 abs (bf16 output)
__device__ inline float gelu_fast(float v) {
  float vc = fminf(fmaxf(v, -8.f), 8.f);
  float e = __expf(1.5957691216f * vc + 0.071354816f * vc * vc * vc);
  return v * e * __builtin_amdgcn_rcpf(e + 1.f);
}

// ---------------- f32 -> bf16 convert (weights) ----------------
__global__ void k_f2bf(const float* __restrict__ in, unsigned short* __restrict__ out, int n) {
  int i = blockIdx.x * blockDim.x + threadIdx.x;
  int stride = gridDim.x * blockDim.x;
  for (; i < n; i += stride) out[i] = f2bf(in[i]);
}

// ---------------- pack mask into transposed bitfield: maskT[bp][row][lr] bit f = mask[bp][row][f*16+lr]>0
__global__ void k_pack_mask(const int* __restrict__ mask, unsigned short* __restrict__ mt) {
  int idx = blockIdx.x * 256 + threadIdx.x;  // 128*256*16 = 524288
  int lr = idx & 15;
  int row = (idx >> 4) & 255;
  int bp = idx >> 12;
  const int* mp = mask + ((size_t)bp * NN + row) * NN;
  unsigned v = 0;
#pragma unroll
  for (int f = 0; f < 16; ++f) v |= (unsigned)(mp[f * 16 + lr] > 0) << f;
  mt[idx] = (unsigned short)v;
}

// ---------------- pack pos transposed bf16: posT[((h*256+row)*16+lr)*16+f] = pos[h][row][f*16+lr]
__global__ void k_pack_pos(const float* __restrict__ pos, unsigned short* __restrict__ pt) {
  int idx = blockIdx.x * 256 + threadIdx.x;  // 8*256*256 = 524288
  int f = idx & 15;
  int lr = (idx >> 4) & 15;
  int row = (idx >> 8) & 255;
  int h = idx >> 16;
  pt[idx] = f2bf(pos[((size_t)h * NN + row) * NN + f * 16 + lr]);
}

// ---------------- group norm over N (tokens), per (bp, c) ----------------
__global__ void k_gn(const float* __restrict__ x, const float* __restrict__ w,
                     const float* __restrict__ b, unsigned short* __restrict__ out) {
  int bp = blockIdx.x >> 1;
  int c = ((blockIdx.x & 1) << 8) + threadIdx.x;
  const float* xp = x + (size_t)bp * NN * CC + c;
  float s = 0.f, sq = 0.f;
  for (int n = 0; n < NN; ++n) { float v = xp[(size_t)n * CC]; s += v; sq += v * v; }
  float mean = s * (1.f / NN);
  float var = sq * (1.f / NN) - mean * mean;
  float rstd = rsqrtf(var + EPS);
  float ww = w[c], bb = b[c];
  unsigned short* op = out + (size_t)bp * NN * CC + c;
  for (int n = 0; n < NN; ++n) {
    float v = xp[(size_t)n * CC];
    op[(size_t)n * CC] = f2bf((v - mean) * rstd * ww + bb);
  }
}

// ---------------- bf16 MFMA GEMM: gload_lds + XOR swizzle, single-buffer (m97 structure) ----
// C = A @ B^T + bias. A[M][K], Bw[Nn][K] row-major bf16.
// EPI 0: out bf16 = v + bias
// EPI 1: out bf16 = gelu(v + bias)
// EPI 2: out f32  = resid + v + bias
// EPI 3: qkv split-store: Q(*0.125) -> qb[bp*H+h][m][d], K -> kb, V -> vtb[bp*H+h][d][m]
template <int EPI>
__global__ __launch_bounds__(256) void k_gemm(const unsigned short* __restrict__ A,
                                              const unsigned short* __restrict__ Bw,
                                              const float* __restrict__ bias,
                                              const float* __restrict__ resid,
                                              unsigned short* __restrict__ outb,
                                              float* __restrict__ outf,
                                              unsigned short* __restrict__ qb,
                                              unsigned short* __restrict__ kb,
                                              unsigned short* __restrict__ vtb,
                                              int M, int Nn, int K) {
  constexpr int BM = 128, BN = 128, BK = 64;
  __shared__ unsigned short As[BM * BK];  // 16 KB, linear
  __shared__ unsigned short Bs[BN * BK];  // 16 KB, linear
  int tid = threadIdx.x;
  int lane = tid & 63, w = tid >> 6;
  int wm = w >> 1, wn = w & 1;
  int m0 = blockIdx.y * BM, n0 = blockIdx.x * BN;
  int rowc = lane >> 3;
  int csrc = (lane & 7) ^ (rowc & 7);
  int lr = lane & 15, lg = lane >> 4;
  f32x4_t acc[4][4] = {};
  for (int k0 = 0; k0 < K; k0 += BK) {
#pragma unroll
    for (int it = 0; it < 4; ++it) {
      int chunk = w * 4 + it;
      int grow = chunk * 8 + rowc;
      async_copy16(&As[chunk * 512], &A[(size_t)(m0 + grow) * K + k0 + csrc * 8]);
      async_copy16(&Bs[chunk * 512], &Bw[(size_t)(n0 + grow) * K + k0 + csrc * 8]);
    }
    __syncthreads();
#pragma unroll
    for (int kk = 0; kk < BK; kk += 32) {
      int kslot = (kk >> 3) + lg;
      short8_t af[4], bfr[4];
#pragma unroll
      for (int i = 0; i < 4; ++i) {
        int r = wm * 64 + i * 16 + lr;
        af[i] = *(const short8_t*)&As[r * 64 + ((kslot ^ (r & 7)) * 8)];
      }
#pragma unroll
      for (int j = 0; j < 4; ++j) {
        int r = wn * 64 + j * 16 + lr;
        bfr[j] = *(const short8_t*)&Bs[r * 64 + ((kslot ^ (r & 7)) * 8)];
      }
#pragma unroll
      for (int i = 0; i < 4; ++i)
#pragma unroll
        for (int j = 0; j < 4; ++j)
          acc[i][j] = __builtin_amdgcn_mfma_f32_16x16x32_bf16(af[i], bfr[j], acc[i][j], 0, 0, 0);
    }
    __syncthreads();
  }
#pragma unroll
  for (int i = 0; i < 4; ++i)
#pragma unroll
    for (int j = 0; j < 4; ++j) {
      int col = n0 + wn * 64 + j * 16 + lr;
      float bv = bias[col];
      int row0 = m0 + wm * 64 + i * 16 + lg * 4;
      if (EPI == 3) {
        int which = col >> 9;         // 0=q 1=k 2=v (wave-uniform)
        int hh2 = (col >> 6) & 7;     // head (wave-uniform)
        int d = col & 63;
        int bp_ = row0 >> 8, m = row0 & 255;
        size_t hb = (size_t)(bp_ * HH + hh2);
        if (which == 2) {
          short4_t pk;
#pragma unroll
          for (int r2 = 0; r2 < 4; ++r2) pk[r2] = (short)f2bf(acc[i][j][r2] + bv);
          *(short4_t*)&vtb[(hb * HD + d) * NN + m] = pk;
        } else if (which == 0) {
#pragma unroll
          for (int r2 = 0; r2 < 4; ++r2)
            qb[(hb * NN + m + r2) * HD + d] = f2bf((acc[i][j][r2] + bv) * 0.125f);
        } else {
#pragma unroll
          for (int r2 = 0; r2 < 4; ++r2)
            kb[(hb * NN + m + r2) * HD + d] = f2bf(acc[i][j][r2] + bv);
        }
      } else {
#pragma unroll
        for (int r2 = 0; r2 < 4; ++r2) {
          int row = row0 + r2;
          float v = acc[i][j][r2] + bv;
          size_t off = (size_t)row * Nn + col;
          if (EPI == 0) {
            outb[off] = f2bf(v);
          } else if (EPI == 1) {
            outb[off] = f2bf(gelu_fast(v));
          } else {
            outf[off] = resid[off] + v;
          }
        }
      }
    }
}

// ---------------- fused attention v4: 2 q-chains per wave (K/V fragment reuse, 2x MLP) -------
// grid: (2, H, BP); 256 threads = 4 waves; wave owns 32 q-rows = 2 independent 16-row chains.
__global__ __launch_bounds__(256, 2) void k_attn4(const unsigned short* __restrict__ qb,
                                                  const unsigned short* __restrict__ kb,
                                                  const unsigned short* __restrict__ vtb,
                                                  const unsigned short* __restrict__ maskT,
                                                  const unsigned short* __restrict__ posT,
                                                  unsigned short* __restrict__ attn_out) {
  constexpr int LMD = NN + 8;  // 264 elems; 2-way bank conflict (free)
  __shared__ unsigned short ps[128 * LMD];  // 66 KB
  int qt = blockIdx.x, h = blockIdx.y, bp = blockIdx.z;
  int tid = threadIdx.x, lane = tid & 63, w = tid >> 6;
  int lr = lane & 15, lg = lane >> 4;
  int q0w = qt * 128 + w * 32;  // wave's first q row
  size_t bh = (size_t)(bp * HH + h);
  const unsigned short* Q = qb + bh * NN * HD;
  const unsigned short* K = kb + bh * NN * HD;
  const unsigned short* VT = vtb + bh * HD * NN;
  // Q fragments: 2 chains x 2 k-halves
  short8_t qf0[2], qf1[2];
#pragma unroll
  for (int c = 0; c < 2; ++c) {
    qf0[c] = *(const short8_t*)&Q[(size_t)(q0w + c * 16 + lr) * HD + lg * 8];
    qf1[c] = *(const short8_t*)&Q[(size_t)(q0w + c * 16 + lr) * HD + 32 + lg * 8];
  }
  // prefetch packed mask/pos for the wave's 8 rows (2 chains x 4)
  unsigned mbits[2][4];
  short8_t pv0[2][4], pv1[2][4];
#pragma unroll
  for (int c = 0; c < 2; ++c)
#pragma unroll
    for (int r2 = 0; r2 < 4; ++r2) {
      int qrow = q0w + c * 16 + lg * 4 + r2;
      mbits[c][r2] = maskT[((size_t)bp * NN + qrow) * 16 + lr];
      const unsigned short* pp = &posT[(((size_t)h * NN + qrow) * 16 + lr) * 16];
      pv0[c][r2] = *(const short8_t*)&pp[0];
      pv1[c][r2] = *(const short8_t*)&pp[8];
    }
  // QK^T: each K fragment pair feeds BOTH chains (load:MFMA = 1:2)
  f32x4_t sc[2][16] = {};
#pragma unroll
  for (int f = 0; f < 16; ++f) {
    short8_t b0 = *(const short8_t*)&K[(size_t)(f * 16 + lr) * HD + lg * 8];
    short8_t b1 = *(const short8_t*)&K[(size_t)(f * 16 + lr) * HD + 32 + lg * 8];
    sc[0][f] = __builtin_amdgcn_mfma_f32_16x16x32_bf16(qf0[0], b0, sc[0][f], 0, 0, 0);
    sc[1][f] = __builtin_amdgcn_mfma_f32_16x16x32_bf16(qf0[1], b0, sc[1][f], 0, 0, 0);
    sc[0][f] = __builtin_amdgcn_mfma_f32_16x16x32_bf16(qf1[0], b1, sc[0][f], 0, 0, 0);
    sc[1][f] = __builtin_amdgcn_mfma_f32_16x16x32_bf16(qf1[1], b1, sc[1][f], 0, 0, 0);
  }
  // mask + pos + softmax (scale pre-folded into Q)
#pragma unroll
  for (int c = 0; c < 2; ++c)
#pragma unroll
    for (int r2 = 0; r2 < 4; ++r2) {
      float mx = -3.0e38f;
#pragma unroll
      for (int f = 0; f < 16; ++f) {
        float pw = bf2f((unsigned short)((f < 8) ? pv0[c][r2][f] : pv1[c][r2][f - 8]));
        float s = ((mbits[c][r2] >> f) & 1) ? (sc[c][f][r2] + pw) : -1.0e9f;
        sc[c][f][r2] = s;
        mx = fmaxf(mx, s);
      }
      for (int d2 = 1; d2 < 16; d2 <<= 1) mx = fmaxf(mx, __shfl_xor(mx, d2));
      float sum = 0.f;
#pragma unroll
      for (int f = 0; f < 16; ++f) { float e = __expf(sc[c][f][r2] - mx); sc[c][f][r2] = e; sum += e; }
      for (int d2 = 1; d2 < 16; d2 <<= 1) sum += __shfl_xor(sum, d2);
      float inv = 1.f / sum;
      int prow = w * 32 + c * 16 + lg * 4 + r2;
#pragma unroll
      for (int f = 0; f < 16; ++f) ps[prow * LMD + f * 16 + lr] = f2bf(sc[c][f][r2] * inv);
    }
  // PV: each VT fragment feeds both chains; P rows wave-private (no block barrier)
  f32x4_t ao[2][4] = {};
#pragma unroll
  for (int kt = 0; kt < 8; ++kt) {
    short8_t a0 = *(const short8_t*)&ps[(w * 32 + lr) * LMD + kt * 32 + lg * 8];
    short8_t a1 = *(const short8_t*)&ps[(w * 32 + 16 + lr) * LMD + kt * 32 + lg * 8];
#pragma unroll
    for (int f = 0; f < 4; ++f) {
      short8_t b = *(const short8_t*)&VT[(size_t)(f * 16 + lr) * NN + kt * 32 + lg * 8];
      ao[0][f] = __builtin_amdgcn_mfma_f32_16x16x32_bf16(a0, b, ao[0][f], 0, 0, 0);
      ao[1][f] = __builtin_amdgcn_mfma_f32_16x16x32_bf16(a1, b, ao[1][f], 0, 0, 0);
    }
  }
#pragma unroll
  for (int c = 0; c < 2; ++c)
#pragma unroll
    for (int f = 0; f < 4; ++f)
#pragma unroll
      for (int r2 = 0; r2 < 4; ++r2) {
        int token = bp * NN + q0w + c * 16 + lg * 4 + r2;
        int d = f * 16 + lr;
        attn_out[(size_t)token * CC + h * HD + d] = f2bf(ao[c][f][r2]);
      }
}

extern "C" void kernel_launch(void* const* d_in, const int* in_sizes, int n_in,
                              void* d_out, int out_size, void* d_ws, size_t ws_size,
                              hipStream_t stream) {
  const float* x      = (const float*)d_in[0];
  const int*   mask   = (const int*)d_in[1];
  const float* pos    = (const float*)d_in[2];
  const float* n1w    = (const float*)d_in[3];
  const float* n1b    = (const float*)d_in[4];
  const float* qkv_w  = (const float*)d_in[5];
  const float* qkv_b  = (const float*)d_in[6];
  const float* proj_w = (const float*)d_in[7];
  const float* proj_b = (const float*)d_in[8];
  const float* n2w    = (const float*)d_in[9];
  const float* n2b    = (const float*)d_in[10];
  const float* w1     = (const float*)d_in[11];
  const float* b1     = (const float*)d_in[12];
  const float* w2     = (const float*)d_in[13];
  const float* b2     = (const float*)d_in[14];
  float* out = (float*)d_out;
  char* ws = (char*)d_ws;

  size_t off = 0;
  auto alloc = [&](size_t bytes) { size_t o = off; off += (bytes + 255) & ~(size_t)255; return o; };
  unsigned short* wqkv  = (unsigned short*)(ws + alloc((size_t)3 * CC * CC * 2));
  unsigned short* wproj = (unsigned short*)(ws + alloc((size_t)CC * CC * 2));
  unsigned short* wm1   = (unsigned short*)(ws + alloc((size_t)MLPD * CC * 2));
  unsigned short* wm2   = (unsigned short*)(ws + alloc((size_t)CC * MLPD * 2));
  unsigned short* maskT = (unsigned short*)(ws + alloc((size_t)BP * NN * 16 * 2));     // 1 MB
  unsigned short* posT  = (unsigned short*)(ws + alloc((size_t)HH * NN * NN * 2));     // 1 MB
  unsigned short* xn    = (unsigned short*)(ws + alloc((size_t)MTOT * CC * 2));   // 32 MB
  float*          x1    = (float*)(ws + alloc((size_t)MTOT * CC * 4));            // 64 MB
  size_t region = alloc((size_t)MTOT * MLPD * 2);                                 // 128 MB shared region
  const size_t BUFE = (size_t)MTOT * CC;  // elems per 32MB buffer
  unsigned short* qbuf  = (unsigned short*)(ws + region);
  unsigned short* kbuf  = qbuf + BUFE;
  unsigned short* vtbuf = qbuf + 2 * BUFE;
  unsigned short* attnb = qbuf + 3 * BUFE;
  unsigned short* hbuf  = (unsigned short*)(ws + region);  // reuses all 4 (dead by MLP time)

  // weight conversions + packs
  k_f2bf<<<1024, 256, 0, stream>>>(qkv_w, wqkv, 3 * CC * CC);
  k_f2bf<<<1024, 256, 0, stream>>>(proj_w, wproj, CC * CC);
  k_f2bf<<<1024, 256, 0, stream>>>(w1, wm1, MLPD * CC);
  k_f2bf<<<1024, 256, 0, stream>>>(w2, wm2, CC * MLPD);
  k_pack_mask<<<2048, 256, 0, stream>>>(mask, maskT);
  k_pack_pos<<<2048, 256, 0, stream>>>(pos, posT);

  // norm1
  k_gn<<<BP * 2, 256, 0, stream>>>(x, n1w, n1b, xn);
  // qkv = xn @ qkv_w^T + b, split-stored into q(*scale)/k/v^T head-major buffers
  k_gemm<3><<<dim3(3 * CC / 128, MTOT / 128), 256, 0, stream>>>(xn, wqkv, qkv_b, nullptr, nullptr, nullptr, qbuf, kbuf, vtbuf, MTOT, 3 * CC, CC);
  // attention
  k_attn4<<<dim3(2, HH, BP), 256, 0, stream>>>(qbuf, kbuf, vtbuf, maskT, posT, attnb);
  // x1 = x + attn @ proj_w^T + proj_b
  k_gemm<2><<<dim3(CC / 128, MTOT / 128), 256, 0, stream>>>(attnb, wproj, proj_b, x, nullptr, x1, nullptr, nullptr, nullptr, MTOT, CC, CC);
  // norm2
  k_gn<<<BP * 2, 256, 0, stream>>>(x1, n2w, n2b, xn);
  // h = gelu(xn @ w1^T + b1)
  k_gemm<1><<<dim3(MLPD / 128, MTOT / 128), 256, 0, stream>>>(xn, wm1, b1, nullptr, hbuf, nullptr, nullptr, nullptr, nullptr, MTOT, MLPD, CC);
  // out = x1 + h @ w2^T + b2
  k_gemm<2><<<dim3(CC / 128, MTOT / 128), 256, 0, stream>>>(hbuf, wm2, b2, x1, nullptr, out, nullptr, nullptr, nullptr, MTOT, CC, MLPD);
}

// Round 11
// 526.615 us; speedup vs baseline: 1.8543x; 1.0026x over previous
//
#include <hip/hip_runtime.h>
#include <hip/hip_bf16.h>

// Problem constants
constexpr int BB = 2, PP = 64, NN = 256, CC = 512, HH = 8, HD = 64, MLPD = 2048;
constexpr int BP = BB * PP;       // 128
constexpr int MTOT = BP * NN;     // 32768
constexpr float EPS = 1e-5f;

typedef __attribute__((ext_vector_type(8))) short short8_t;
typedef __attribute__((ext_vector_type(4))) short short4_t;
typedef __attribute__((ext_vector_type(4))) float f32x4_t;
typedef __attribute__((ext_vector_type(2))) unsigned int uint2_t;

__device__ inline unsigned short f2bf(float f) {
  union { float f; unsigned u; } v; v.f = f;
  unsigned r = v.u + 0x7fffu + ((v.u >> 16) & 1u);
  return (unsigned short)(r >> 16);
}
__device__ inline float bf2f(unsigned short u) {
  union { unsigned u; float f; } v; v.u = ((unsigned)u) << 16;
  return v.f;
}
// pack 2 f32 -> 2 bf16 in one dword (RNE), gfx950 HW op
__device__ inline unsigned int cvt_pk_bf16(float lo, float hi) {
  unsigned int r;
  asm("v_cvt_pk_bf16_f32 %0, %1, %2" : "=v"(r) : "v"(lo), "v"(hi));
  return r;
}

// async 16B global -> LDS (wave-uniform LDS base, per-lane global addr; HW writes base + lane*16)
__device__ inline void async_copy16(unsigned short* lds_base, const unsigned short* g) {
  __builtin_amdgcn_global_load_lds((const __attribute__((address_space(1))) unsigned int*)g,
                                   (__attribute__((address_space(3))) unsigned int*)lds_base,
                                   16, 0, 0);
}

// cheap exact-enough gelu: tanh form, err<~5e-4 abs (bf16 output)
__device__ inline float gelu_fast(float v) {
  float vc = fminf(fmaxf(v, -8.f), 8.f);
  float e = __expf(1.5957691216f * vc + 0.071354816f * vc * vc * vc);
  return v * e * __builtin_amdgcn_rcpf(e + 1.f);
}

// ---------------- f32 -> bf16 convert (weights) ----------------
__global__ void k_f2bf(const float* __restrict__ in, unsigned short* __restrict__ out, int n) {
  int i = blockIdx.x * blockDim.x + threadIdx.x;
  int stride = gridDim.x * blockDim.x;
  for (; i < n; i += stride) out[i] = f2bf(in[i]);
}

// ---------------- pack mask into transposed bitfield: maskT[bp][row][lr] bit f = mask[bp][row][f*16+lr]>0
__global__ void k_pack_mask(const int* __restrict__ mask, unsigned short* __restrict__ mt) {
  int idx = blockIdx.x * 256 + threadIdx.x;  // 128*256*16 = 524288
  int lr = idx & 15;
  int row = (idx >> 4) & 255;
  int bp = idx >> 12;
  const int* mp = mask + ((size_t)bp * NN + row) * NN;
  unsigned v = 0;
#pragma unroll
  for (int f = 0; f < 16; ++f) v |= (unsigned)(mp[f * 16 + lr] > 0) << f;
  mt[idx] = (unsigned short)v;
}

// ---------------- pack pos transposed bf16: posT[((h*256+row)*16+lr)*16+f] = pos[h][row][f*16+lr]
__global__ void k_pack_pos(const float* __restrict__ pos, unsigned short* __restrict__ pt) {
  int idx = blockIdx.x * 256 + threadIdx.x;  // 8*256*256 = 524288
  int f = idx & 15;
  int lr = (idx >> 4) & 15;
  int row = (idx >> 8) & 255;
  int h = idx >> 16;
  pt[idx] = f2bf(pos[((size_t)h * NN + row) * NN + f * 16 + lr]);
}

// ---------------- group norm over N (tokens), per (bp, c) ----------------
__global__ void k_gn(const float* __restrict__ x, const float* __restrict__ w,
                     const float* __restrict__ b, unsigned short* __restrict__ out) {
  int bp = blockIdx.x >> 1;
  int c = ((blockIdx.x & 1) << 8) + threadIdx.x;
  const float* xp = x + (size_t)bp * NN * CC + c;
  float s = 0.f, sq = 0.f;
  for (int n = 0; n < NN; ++n) { float v = xp[(size_t)n * CC]; s += v; sq += v * v; }
  float mean = s * (1.f / NN);
  float var = sq * (1.f / NN) - mean * mean;
  float rstd = rsqrtf(var + EPS);
  float ww = w[c], bb = b[c];
  unsigned short* op = out + (size_t)bp * NN * CC + c;
  for (int n = 0; n < NN; ++n) {
    float v = xp[(size_t)n * CC];
    op[(size_t)n * CC] = f2bf((v - mean) * rstd * ww + bb);
  }
}

// ---------------- bf16 MFMA GEMM: gload_lds + XOR swizzle, single-buffer ----
// C = A @ B^T + bias. A[M][K], Bw[Nn][K] row-major bf16.
// EPI 1/2 use SWAPPED mfma operands: lane holds 4 consecutive output COLS at one row
//   -> float4 bias/resid, cvt_pk packed bf16, 8B/16B vector stores.
// EPI 1: out bf16 = gelu(v + bias)
// EPI 2: out f32  = resid + v + bias
// EPI 3: qkv split-store (unswapped): Q(*0.125) -> qb, K -> kb, V -> vtb[bp*H+h][d][m]
template <int EPI>
__global__ __launch_bounds__(256) void k_gemm(const unsigned short* __restrict__ A,
                                              const unsigned short* __restrict__ Bw,
                                              const float* __restrict__ bias,
                                              const float* __restrict__ resid,
                                              unsigned short* __restrict__ outb,
                                              float* __restrict__ outf,
                                              unsigned short* __restrict__ qb,
                                              unsigned short* __restrict__ kb,
                                              unsigned short* __restrict__ vtb,
                                              int M, int Nn, int K) {
  constexpr bool SW = (EPI != 3);
  constexpr int BM = 128, BN = 128, BK = 64;
  __shared__ unsigned short As[BM * BK];  // 16 KB, linear
  __shared__ unsigned short Bs[BN * BK];  // 16 KB, linear
  int tid = threadIdx.x;
  int lane = tid & 63, w = tid >> 6;
  int wm = w >> 1, wn = w & 1;
  int m0 = blockIdx.y * BM, n0 = blockIdx.x * BN;
  int rowc = lane >> 3;
  int csrc = (lane & 7) ^ (rowc & 7);
  int lr = lane & 15, lg = lane >> 4;
  f32x4_t acc[4][4] = {};
  for (int k0 = 0; k0 < K; k0 += BK) {
#pragma unroll
    for (int it = 0; it < 4; ++it) {
      int chunk = w * 4 + it;
      int grow = chunk * 8 + rowc;
      async_copy16(&As[chunk * 512], &A[(size_t)(m0 + grow) * K + k0 + csrc * 8]);
      async_copy16(&Bs[chunk * 512], &Bw[(size_t)(n0 + grow) * K + k0 + csrc * 8]);
    }
    __syncthreads();
#pragma unroll
    for (int kk = 0; kk < BK; kk += 32) {
      int kslot = (kk >> 3) + lg;
      short8_t af[4], bfr[4];
#pragma unroll
      for (int i = 0; i < 4; ++i) {
        int r = wm * 64 + i * 16 + lr;
        af[i] = *(const short8_t*)&As[r * 64 + ((kslot ^ (r & 7)) * 8)];
      }
#pragma unroll
      for (int j = 0; j < 4; ++j) {
        int r = wn * 64 + j * 16 + lr;
        bfr[j] = *(const short8_t*)&Bs[r * 64 + ((kslot ^ (r & 7)) * 8)];
      }
#pragma unroll
      for (int i = 0; i < 4; ++i)
#pragma unroll
        for (int j = 0; j < 4; ++j) {
          if (SW)
            acc[i][j] = __builtin_amdgcn_mfma_f32_16x16x32_bf16(bfr[j], af[i], acc[i][j], 0, 0, 0);
          else
            acc[i][j] = __builtin_amdgcn_mfma_f32_16x16x32_bf16(af[i], bfr[j], acc[i][j], 0, 0, 0);
        }
    }
    __syncthreads();
  }
  if (SW) {
    // lane holds row m = m0+wm*64+i*16+lr, cols n0c..n0c+3 with n0c = n0+wn*64+j*16+lg*4
#pragma unroll
    for (int i = 0; i < 4; ++i) {
      int m = m0 + wm * 64 + i * 16 + lr;
#pragma unroll
      for (int j = 0; j < 4; ++j) {
        int n0c = n0 + wn * 64 + j * 16 + lg * 4;
        f32x4_t bv = *(const f32x4_t*)&bias[n0c];
        size_t off = (size_t)m * Nn + n0c;
        if (EPI == 1) {
          float g0 = gelu_fast(acc[i][j][0] + bv[0]);
          float g1 = gelu_fast(acc[i][j][1] + bv[1]);
          float g2 = gelu_fast(acc[i][j][2] + bv[2]);
          float g3 = gelu_fast(acc[i][j][3] + bv[3]);
          uint2_t pk;
          pk[0] = cvt_pk_bf16(g0, g1);
          pk[1] = cvt_pk_bf16(g2, g3);
          *(uint2_t*)&outb[off] = pk;
        } else {  // EPI == 2
          f32x4_t rv = *(const f32x4_t*)&resid[off];
          f32x4_t o;
#pragma unroll
          for (int r2 = 0; r2 < 4; ++r2) o[r2] = rv[r2] + acc[i][j][r2] + bv[r2];
          *(f32x4_t*)&outf[off] = o;
        }
      }
    }
  } else {
    // EPI == 3, unswapped: lane holds col = ...+lr, rows row0..row0+3
#pragma unroll
    for (int i = 0; i < 4; ++i)
#pragma unroll
      for (int j = 0; j < 4; ++j) {
        int col = n0 + wn * 64 + j * 16 + lr;
        float bv = bias[col];
        int row0 = m0 + wm * 64 + i * 16 + lg * 4;
        int which = col >> 9;         // 0=q 1=k 2=v (wave-uniform)
        int hh2 = (col >> 6) & 7;     // head (wave-uniform)
        int d = col & 63;
        int bp_ = row0 >> 8, m = row0 & 255;
        size_t hb = (size_t)(bp_ * HH + hh2);
        if (which == 2) {
          short4_t pk;
#pragma unroll
          for (int r2 = 0; r2 < 4; ++r2) pk[r2] = (short)f2bf(acc[i][j][r2] + bv);
          *(short4_t*)&vtb[(hb * HD + d) * NN + m] = pk;
        } else if (which == 0) {
#pragma unroll
          for (int r2 = 0; r2 < 4; ++r2)
            qb[(hb * NN + m + r2) * HD + d] = f2bf((acc[i][j][r2] + bv) * 0.125f);
        } else {
#pragma unroll
          for (int r2 = 0; r2 < 4; ++r2)
            kb[(hb * NN + m + r2) * HD + d] = f2bf(acc[i][j][r2] + bv);
        }
      }
  }
}

// ---------------- fused attention v4: 2 q-chains per wave (K/V fragment reuse) -------
// grid: (2, H, BP); 256 threads = 4 waves; wave owns 32 q-rows = 2 independent 16-row chains.
__global__ __launch_bounds__(256, 2) void k_attn4(const unsigned short* __restrict__ qb,
                                                  const unsigned short* __restrict__ kb,
                                                  const unsigned short* __restrict__ vtb,
                                                  const unsigned short* __restrict__ maskT,
                                                  const unsigned short* __restrict__ posT,
                                                  unsigned short* __restrict__ attn_out) {
  constexpr int LMD = NN + 8;  // 264 elems; 2-way bank conflict (free)
  __shared__ unsigned short ps[128 * LMD];  // 66 KB
  int qt = blockIdx.x, h = blockIdx.y, bp = blockIdx.z;
  int tid = threadIdx.x, lane = tid & 63, w = tid >> 6;
  int lr = lane & 15, lg = lane >> 4;
  int q0w = qt * 128 + w * 32;  // wave's first q row
  size_t bh = (size_t)(bp * HH + h);
  const unsigned short* Q = qb + bh * NN * HD;
  const unsigned short* K = kb + bh * NN * HD;
  const unsigned short* VT = vtb + bh * HD * NN;
  // Q fragments: 2 chains x 2 k-halves
  short8_t qf0[2], qf1[2];
#pragma unroll
  for (int c = 0; c < 2; ++c) {
    qf0[c] = *(const short8_t*)&Q[(size_t)(q0w + c * 16 + lr) * HD + lg * 8];
    qf1[c] = *(const short8_t*)&Q[(size_t)(q0w + c * 16 + lr) * HD + 32 + lg * 8];
  }
  // prefetch packed mask/pos for the wave's 8 rows (2 chains x 4)
  unsigned mbits[2][4];
  short8_t pv0[2][4], pv1[2][4];
#pragma unroll
  for (int c = 0; c < 2; ++c)
#pragma unroll
    for (int r2 = 0; r2 < 4; ++r2) {
      int qrow = q0w + c * 16 + lg * 4 + r2;
      mbits[c][r2] = maskT[((size_t)bp * NN + qrow) * 16 + lr];
      const unsigned short* pp = &posT[(((size_t)h * NN + qrow) * 16 + lr) * 16];
      pv0[c][r2] = *(const short8_t*)&pp[0];
      pv1[c][r2] = *(const short8_t*)&pp[8];
    }
  // QK^T: each K fragment pair feeds BOTH chains (load:MFMA = 1:2)
  f32x4_t sc[2][16] = {};
#pragma unroll
  for (int f = 0; f < 16; ++f) {
    short8_t b0 = *(const short8_t*)&K[(size_t)(f * 16 + lr) * HD + lg * 8];
    short8_t b1 = *(const short8_t*)&K[(size_t)(f * 16 + lr) * HD + 32 + lg * 8];
    sc[0][f] = __builtin_amdgcn_mfma_f32_16x16x32_bf16(qf0[0], b0, sc[0][f], 0, 0, 0);
    sc[1][f] = __builtin_amdgcn_mfma_f32_16x16x32_bf16(qf0[1], b0, sc[1][f], 0, 0, 0);
    sc[0][f] = __builtin_amdgcn_mfma_f32_16x16x32_bf16(qf1[0], b1, sc[0][f], 0, 0, 0);
    sc[1][f] = __builtin_amdgcn_mfma_f32_16x16x32_bf16(qf1[1], b1, sc[1][f], 0, 0, 0);
  }
  // mask + pos + softmax (scale pre-folded into Q)
#pragma unroll
  for (int c = 0; c < 2; ++c)
#pragma unroll
    for (int r2 = 0; r2 < 4; ++r2) {
      float mx = -3.0e38f;
#pragma unroll
      for (int f = 0; f < 16; ++f) {
        float pw = bf2f((unsigned short)((f < 8) ? pv0[c][r2][f] : pv1[c][r2][f - 8]));
        float s = ((mbits[c][r2] >> f) & 1) ? (sc[c][f][r2] + pw) : -1.0e9f;
        sc[c][f][r2] = s;
        mx = fmaxf(mx, s);
      }
      for (int d2 = 1; d2 < 16; d2 <<= 1) mx = fmaxf(mx, __shfl_xor(mx, d2));
      float sum = 0.f;
#pragma unroll
      for (int f = 0; f < 16; ++f) { float e = __expf(sc[c][f][r2] - mx); sc[c][f][r2] = e; sum += e; }
      for (int d2 = 1; d2 < 16; d2 <<= 1) sum += __shfl_xor(sum, d2);
      float inv = 1.f / sum;
      int prow = w * 32 + c * 16 + lg * 4 + r2;
#pragma unroll
      for (int f = 0; f < 16; ++f) ps[prow * LMD + f * 16 + lr] = f2bf(sc[c][f][r2] * inv);
    }
  // PV: each VT fragment feeds both chains; P rows wave-private (no block barrier)
  f32x4_t ao[2][4] = {};
#pragma unroll
  for (int kt = 0; kt < 8; ++kt) {
    short8_t a0 = *(const short8_t*)&ps[(w * 32 + lr) * LMD + kt * 32 + lg * 8];
    short8_t a1 = *(const short8_t*)&ps[(w * 32 + 16 + lr) * LMD + kt * 32 + lg * 8];
#pragma unroll
    for (int f = 0; f < 4; ++f) {
      short8_t b = *(const short8_t*)&VT[(size_t)(f * 16 + lr) * NN + kt * 32 + lg * 8];
      ao[0][f] = __builtin_amdgcn_mfma_f32_16x16x32_bf16(a0, b, ao[0][f], 0, 0, 0);
      ao[1][f] = __builtin_amdgcn_mfma_f32_16x16x32_bf16(a1, b, ao[1][f], 0, 0, 0);
    }
  }
#pragma unroll
  for (int c = 0; c < 2; ++c)
#pragma unroll
    for (int f = 0; f < 4; ++f)
#pragma unroll
      for (int r2 = 0; r2 < 4; ++r2) {
        int token = bp * NN + q0w + c * 16 + lg * 4 + r2;
        int d = f * 16 + lr;
        attn_out[(size_t)token * CC + h * HD + d] = f2bf(ao[c][f][r2]);
      }
}

extern "C" void kernel_launch(void* const* d_in, const int* in_sizes, int n_in,
                              void* d_out, int out_size, void* d_ws, size_t ws_size,
                              hipStream_t stream) {
  const float* x      = (const float*)d_in[0];
  const int*   mask   = (const int*)d_in[1];
  const float* pos    = (const float*)d_in[2];
  const float* n1w    = (const float*)d_in[3];
  const float* n1b    = (const float*)d_in[4];
  const float* qkv_w  = (const float*)d_in[5];
  const float* qkv_b  = (const float*)d_in[6];
  const float* proj_w = (const float*)d_in[7];
  const float* proj_b = (const float*)d_in[8];
  const float* n2w    = (const float*)d_in[9];
  const float* n2b    = (const float*)d_in[10];
  const float* w1     = (const float*)d_in[11];
  const float* b1     = (const float*)d_in[12];
  const float* w2     = (const float*)d_in[13];
  const float* b2     = (const float*)d_in[14];
  float* out = (float*)d_out;
  char* ws = (char*)d_ws;

  size_t off = 0;
  auto alloc = [&](size_t bytes) { size_t o = off; off += (bytes + 255) & ~(size_t)255; return o; };
  unsigned short* wqkv  = (unsigned short*)(ws + alloc((size_t)3 * CC * CC * 2));
  unsigned short* wproj = (unsigned short*)(ws + alloc((size_t)CC * CC * 2));
  unsigned short* wm1   = (unsigned short*)(ws + alloc((size_t)MLPD * CC * 2));
  unsigned short* wm2   = (unsigned short*)(ws + alloc((size_t)CC * MLPD * 2));
  unsigned short* maskT = (unsigned short*)(ws + alloc((size_t)BP * NN * 16 * 2));     // 1 MB
  unsigned short* posT  = (unsigned short*)(ws + alloc((size_t)HH * NN * NN * 2));     // 1 MB
  unsigned short* xn    = (unsigned short*)(ws + alloc((size_t)MTOT * CC * 2));   // 32 MB
  float*          x1    = (float*)(ws + alloc((size_t)MTOT * CC * 4));            // 64 MB
  size_t region = alloc((size_t)MTOT * MLPD * 2);                                 // 128 MB shared region
  const size_t BUFE = (size_t)MTOT * CC;  // elems per 32MB buffer
  unsigned short* qbuf  = (unsigned short*)(ws + region);
  unsigned short* kbuf  = qbuf + BUFE;
  unsigned short* vtbuf = qbuf + 2 * BUFE;
  unsigned short* attnb = qbuf + 3 * BUFE;
  unsigned short* hbuf  = (unsigned short*)(ws + region);  // reuses all 4 (dead by MLP time)

  // weight conversions + packs
  k_f2bf<<<1024, 256, 0, stream>>>(qkv_w, wqkv, 3 * CC * CC);
  k_f2bf<<<1024, 256, 0, stream>>>(proj_w, wproj, CC * CC);
  k_f2bf<<<1024, 256, 0, stream>>>(w1, wm1, MLPD * CC);
  k_f2bf<<<1024, 256, 0, stream>>>(w2, wm2, CC * MLPD);
  k_pack_mask<<<2048, 256, 0, stream>>>(mask, maskT);
  k_pack_pos<<<2048, 256, 0, stream>>>(pos, posT);

  // norm1
  k_gn<<<BP * 2, 256, 0, stream>>>(x, n1w, n1b, xn);
  // qkv = xn @ qkv_w^T + b, split-stored into q(*scale)/k/v^T head-major buffers
  k_gemm<3><<<dim3(3 * CC / 128, MTOT / 128), 256, 0, stream>>>(xn, wqkv, qkv_b, nullptr, nullptr, nullptr, qbuf, kbuf, vtbuf, MTOT, 3 * CC, CC);
  // attention
  k_attn4<<<dim3(2, HH, BP), 256, 0, stream>>>(qbuf, kbuf, vtbuf, maskT, posT, attnb);
  // x1 = x + attn @ proj_w^T + proj_b
  k_gemm<2><<<dim3(CC / 128, MTOT / 128), 256, 0, stream>>>(attnb, wproj, proj_b, x, nullptr, x1, nullptr, nullptr, nullptr, MTOT, CC, CC);
  // norm2
  k_gn<<<BP * 2, 256, 0, stream>>>(x1, n2w, n2b, xn);
  // h = gelu(xn @ w1^T + b1)
  k_gemm<1><<<dim3(MLPD / 128, MTOT / 128), 256, 0, stream>>>(xn, wm1, b1, nullptr, hbuf, nullptr, nullptr, nullptr, nullptr, MTOT, MLPD, CC);
  // out = x1 + h @ w2^T + b2
  k_gemm<2><<<dim3(CC / 128, MTOT / 128), 256, 0, stream>>>(hbuf, wm2, b2, x1, nullptr, out, nullptr, nullptr, nullptr, MTOT, CC, MLPD);
}